// Round 5
// baseline (13588.844 us; speedup 1.0000x reference)
//
#include <hip/hip_runtime.h>

typedef __attribute__((ext_vector_type(8))) short short8;
typedef __attribute__((ext_vector_type(4))) float f32x4;

static constexpr int BN    = 512;
static constexpr int ID    = 1024;
static constexpr int HDm   = 2048;
static constexpr int LD    = 1000;
static constexpr int TMAXc = 32;
static constexpr float ALPHAc = 0.05f;

// ---------------- bf16 split helpers (x ~= hi + lo, each bf16) ----------------
__device__ __forceinline__ unsigned short f2bf(float x) {
    unsigned u = __float_as_uint(x);
    u += 0x7fffu + ((u >> 16) & 1u);           // RNE
    return (unsigned short)(u >> 16);
}
__device__ __forceinline__ float bf2f(unsigned short h) {
    return __uint_as_float(((unsigned)h) << 16);
}
__device__ __forceinline__ void split2(float x, unsigned short& hi, unsigned short& lo) {
    hi = f2bf(x);
    lo = f2bf(x - bf2f(hi));
}

// ---------------------------------------------------------------------------
// Custom 2-level grid barrier (256 blocks). ROCm's cg grid.sync serializes 256
// RMWs on ONE counter (~40us); this splits arrival across 16 lines + root.
// bar layout (ints): [0..63] subs[slot][16], [64..67] root[slot], [68] release.
// ---------------------------------------------------------------------------
__device__ __forceinline__ void gbar(int* bar, int idx)
{
    __builtin_amdgcn_fence(__ATOMIC_RELEASE, "agent");   // make our stores visible
    __syncthreads();
    if (threadIdx.x == 0) {
        const int slot = idx & 3;
        int* sc = bar + slot * 16 + (blockIdx.x & 15);
        int a = __hip_atomic_fetch_add(sc, 1, __ATOMIC_ACQ_REL, __HIP_MEMORY_SCOPE_AGENT);
        if (a == 15) {                                   // last of 16-block group
            int* rc = bar + 64 + slot;
            int r = __hip_atomic_fetch_add(rc, 1, __ATOMIC_ACQ_REL, __HIP_MEMORY_SCOPE_AGENT);
            if (r == 15) {                               // global last: reset slot, publish
#pragma unroll
                for (int g = 0; g < 16; ++g)
                    __hip_atomic_store(bar + slot * 16 + g, 0, __ATOMIC_RELAXED, __HIP_MEMORY_SCOPE_AGENT);
                __hip_atomic_store(rc, 0, __ATOMIC_RELAXED, __HIP_MEMORY_SCOPE_AGENT);
                __hip_atomic_fetch_add(bar + 68, 1, __ATOMIC_RELEASE, __HIP_MEMORY_SCOPE_AGENT);
            }
        }
        while (__hip_atomic_load(bar + 68, __ATOMIC_ACQUIRE, __HIP_MEMORY_SCOPE_AGENT) < idx + 1)
            __builtin_amdgcn_s_sleep(8);
    }
    __syncthreads();
    __builtin_amdgcn_fence(__ATOMIC_ACQUIRE, "agent");   // see others' stores
}

// ---------------------------------------------------------------------------
// 64x64 tile, 1024 threads (16 waves, one 16x16 C-fragment each), K-step 64,
// 2-deep register prefetch, split-bf16 3-term MFMA (~fp32 accuracy).
// A fp32 [M,K] row-major; B transposed pre-split bf16 [N,K] (rows = out cols).
// LDS XOR swizzle: byte ^= (row&7)<<4.
// ---------------------------------------------------------------------------
__device__ __forceinline__ void tile64_gemm(
    const float* __restrict__ A, int lda, int row0,
    const unsigned short* __restrict__ BThi, const unsigned short* __restrict__ BTlo,
    int ldk, int col0, int K, char* lds, f32x4& acc)
{
    char* Ah = lds;
    char* Al = lds + 8192;
    char* Bh = lds + 16384;
    char* Bl = lds + 24576;
    const int t = threadIdx.x, lane = t & 63, w = t >> 6;
    const int wrow = w >> 2, wcol = w & 3;
    f32x4 z = {0.f, 0.f, 0.f, 0.f};
    acc = z;

    const int ar = t >> 4, ac = (t & 15) << 2;     // A: 64 rows x 64, float4/thread
    const int br = t >> 4, bc = (t & 15) << 2;     // B: 64 rows x 64, uint2/thread
    const float* Ap = A + (size_t)(row0 + ar) * lda + ac;
    const unsigned short* Bhp = BThi + (size_t)(col0 + br) * ldk + bc;
    const unsigned short* Blp = BTlo + (size_t)(col0 + br) * ldk + bc;
    const int asb = (ar * 128 + ac * 2) ^ ((ar & 7) << 4);
    const int bsb = (br * 128 + bc * 2) ^ ((br & 7) << 4);
    const int colr = wcol * 16 + (lane & 15);
    const int arow = wrow * 16 + (lane & 15);
    const int bb0 = colr * 128, ab0 = arow * 128;
    const int bxor = (colr & 7) << 4, axor = (arow & 7) << 4;
    const int kb0 = (lane >> 4) << 4;

    // 2-deep prefetch pipeline (K >= 128 always here)
    float4 av0 = *(const float4*)(Ap);
    uint2  bh0 = *(const uint2*)(Bhp);
    uint2  bl0 = *(const uint2*)(Blp);
    float4 av1 = *(const float4*)(Ap + 64);
    uint2  bh1 = *(const uint2*)(Bhp + 64);
    uint2  bl1 = *(const uint2*)(Blp + 64);

    for (int k0 = 0; k0 < K; k0 += 64) {
        unsigned short h0, h1, h2, h3, l0, l1, l2, l3;
        split2(av0.x, h0, l0); split2(av0.y, h1, l1);
        split2(av0.z, h2, l2); split2(av0.w, h3, l3);
        uint2 ahp = make_uint2((unsigned)h0 | ((unsigned)h1 << 16),
                               (unsigned)h2 | ((unsigned)h3 << 16));
        uint2 alp = make_uint2((unsigned)l0 | ((unsigned)l1 << 16),
                               (unsigned)l2 | ((unsigned)l3 << 16));
        uint2 bhw = bh0, blw = bl0;
        __syncthreads();                            // prior LDS readers done
        *(uint2*)(Ah + asb) = ahp;
        *(uint2*)(Al + asb) = alp;
        *(uint2*)(Bh + bsb) = bhw;
        *(uint2*)(Bl + bsb) = blw;
        av0 = av1; bh0 = bh1; bl0 = bl1;            // shift pipeline
        if (k0 + 128 < K) {                         // issue loads 2 iters ahead
            av1 = *(const float4*)(Ap + k0 + 128);
            bh1 = *(const uint2*)(Bhp + k0 + 128);
            bl1 = *(const uint2*)(Blp + k0 + 128);
        }
        __syncthreads();
#pragma unroll
        for (int ks = 0; ks < 2; ++ks) {
            const int kb = ks * 64 + kb0;
            short8 bh = *(const short8*)(Bh + ((bb0 + kb) ^ bxor));
            short8 bl = *(const short8*)(Bl + ((bb0 + kb) ^ bxor));
            short8 ah = *(const short8*)(Ah + ((ab0 + kb) ^ axor));
            short8 al = *(const short8*)(Al + ((ab0 + kb) ^ axor));
            acc = __builtin_amdgcn_mfma_f32_16x16x32_bf16(ah, bh, acc, 0, 0, 0);
            acc = __builtin_amdgcn_mfma_f32_16x16x32_bf16(al, bh, acc, 0, 0, 0);
            acc = __builtin_amdgcn_mfma_f32_16x16x32_bf16(ah, bl, acc, 0, 0, 0);
        }
    }
}

// ---------------------------------------------------------------------------
// 32x64 tile, K=2048, 1024 threads; 16 waves = 8 C-fragments x 2 K-halves,
// 128-wide K staging, 2-deep prefetch. LDS swizzle: ^ (row&15)<<4.
// ---------------------------------------------------------------------------
__device__ __forceinline__ void tile32_gemm_ks(
    const float* __restrict__ A, int row0,
    const unsigned short* __restrict__ BThi, const unsigned short* __restrict__ BTlo,
    int col0, char* lds, f32x4& acc, int& s_out, int& p_out)
{
    char* Ah = lds;                  // 32*256   = 8 KB
    char* Al = lds + 8192;           //            8 KB
    char* Bh = lds + 16384;          // 64*256   = 16 KB
    char* Bl = lds + 32768;          //            16 KB
    const int t = threadIdx.x, lane = t & 63, w = t >> 6;
    const int s = w & 7, p = w >> 3;
    s_out = s; p_out = p;
    const int mrow = s >> 2, wcol = s & 3;
    f32x4 z = {0.f, 0.f, 0.f, 0.f};
    acc = z;

    const int ar = t >> 5, ac = (t & 31) << 2;     // A: 32 rows x 128, float4/thread
    const int br = t >> 4, bc = (t & 15) << 3;     // B: 64 rows x 128, uint4/thread
    const float* Ap = A + (size_t)(row0 + ar) * HDm + ac;
    const unsigned short* Bhp = BThi + (size_t)(col0 + br) * HDm + bc;
    const unsigned short* Blp = BTlo + (size_t)(col0 + br) * HDm + bc;
    const int asb = (ar * 256 + ac * 2) ^ ((ar & 15) << 4);
    const int bsb = (br * 256 + bc * 2) ^ ((br & 15) << 4);
    const int colr = wcol * 16 + (lane & 15);
    const int arow = mrow * 16 + (lane & 15);
    const int bb0 = colr * 256, ab0 = arow * 256;
    const int bxor = (colr & 15) << 4, axor = (arow & 15) << 4;
    const int kc = p * 128;
    const int kb0 = (lane >> 4) << 4;

    float4 av0 = *(const float4*)(Ap);
    uint4  bh0 = *(const uint4*)(Bhp);
    uint4  bl0 = *(const uint4*)(Blp);
    float4 av1 = *(const float4*)(Ap + 128);
    uint4  bh1 = *(const uint4*)(Bhp + 128);
    uint4  bl1 = *(const uint4*)(Blp + 128);

    for (int k0 = 0; k0 < HDm; k0 += 128) {
        unsigned short h0, h1, h2, h3, l0, l1, l2, l3;
        split2(av0.x, h0, l0); split2(av0.y, h1, l1);
        split2(av0.z, h2, l2); split2(av0.w, h3, l3);
        uint2 ahp = make_uint2((unsigned)h0 | ((unsigned)h1 << 16),
                               (unsigned)h2 | ((unsigned)h3 << 16));
        uint2 alp = make_uint2((unsigned)l0 | ((unsigned)l1 << 16),
                               (unsigned)l2 | ((unsigned)l3 << 16));
        uint4 bhw = bh0, blw = bl0;
        __syncthreads();
        *(uint2*)(Ah + asb) = ahp;
        *(uint2*)(Al + asb) = alp;
        *(uint4*)(Bh + bsb) = bhw;
        *(uint4*)(Bl + bsb) = blw;
        av0 = av1; bh0 = bh1; bl0 = bl1;
        if (k0 + 256 < HDm) {
            av1 = *(const float4*)(Ap + k0 + 256);
            bh1 = *(const uint4*)(Bhp + k0 + 256);
            bl1 = *(const uint4*)(Blp + k0 + 256);
        }
        __syncthreads();
#pragma unroll
        for (int ks = 0; ks < 2; ++ks) {
            const int kb = kc + ks * 64 + kb0;
            short8 bh = *(const short8*)(Bh + ((bb0 + kb) ^ bxor));
            short8 bl = *(const short8*)(Bl + ((bb0 + kb) ^ bxor));
            short8 ah = *(const short8*)(Ah + ((ab0 + kb) ^ axor));
            short8 al = *(const short8*)(Al + ((ab0 + kb) ^ axor));
            acc = __builtin_amdgcn_mfma_f32_16x16x32_bf16(ah, bh, acc, 0, 0, 0);
            acc = __builtin_amdgcn_mfma_f32_16x16x32_bf16(al, bh, acc, 0, 0, 0);
            acc = __builtin_amdgcn_mfma_f32_16x16x32_bf16(ah, bl, acc, 0, 0, 0);
        }
    }
}

// ---------------------------------------------------------------------------
// Prep kernels
// ---------------------------------------------------------------------------
__global__ void k_init(int* active, int* nact, float* scal, int* bar)
{
    int i = blockIdx.x * blockDim.x + threadIdx.x;
    if (i < BN) active[i] = 1;
    if (i < TMAXc + 1) nact[i] = 0;
    if (i < 8) scal[i] = 0.f;
    if (i < 69) bar[i] = 0;
}

__global__ __launch_bounds__(1024) void k_colsum_wh(const float* __restrict__ RH,
                                                    const float* __restrict__ MH,
                                                    float* scal)
{
    const int col = blockIdx.x * 64 + (threadIdx.x & 63);
    const int rs  = threadIdx.x >> 6;
    float s = 0.f;
    for (int i = rs; i < HDm; i += 16)
        s += fabsf(RH[(size_t)i * HDm + col] * MH[(size_t)i * HDm + col]);
    __shared__ float red[16][64];
    red[rs][threadIdx.x & 63] = s;
    __syncthreads();
    if (threadIdx.x < 64) {
        float c = 0.f;
#pragma unroll
        for (int j = 0; j < 16; ++j) c += red[j][threadIdx.x];
#pragma unroll
        for (int off = 1; off < 64; off <<= 1) c = fmaxf(c, __shfl_xor(c, off));
        if (threadIdx.x == 0)
            atomicMax((unsigned int*)&scal[0], __float_as_uint(c));
    }
}

__global__ __launch_bounds__(1024) void k_colsum_whl(const float* __restrict__ RHL,
                                                     const float* __restrict__ MHL,
                                                     float* scal)
{
    const int col = blockIdx.x * 64 + (threadIdx.x & 63);
    const int rs  = threadIdx.x >> 6;
    float s = 0.f;
    if (col < LD) {
        for (int i = rs; i < HDm; i += 16)
            s += fabsf(RHL[(size_t)i * LD + col] * MHL[(size_t)i * LD + col]);
    }
    __shared__ float red[16][64];
    red[rs][threadIdx.x & 63] = s;
    __syncthreads();
    if (threadIdx.x < 64) {
        float c = 0.f;
#pragma unroll
        for (int j = 0; j < 16; ++j) c += red[j][threadIdx.x];
#pragma unroll
        for (int off = 1; off < 64; off <<= 1) c = fmaxf(c, __shfl_xor(c, off));
        if (threadIdx.x == 0)
            atomicMax((unsigned int*)&scal[1], __float_as_uint(c));
    }
}

__global__ void k_scalars(float* scal)
{
    if (threadIdx.x == 0 && blockIdx.x == 0) {
        scal[2] = 0.95f / fmaxf(scal[0], 1e-8f);   // W_H scale
        scal[3] = scal[1] * 19.f;                  // gamma_coef
    }
}

// Transposed split:  O{hi,lo}[c][r] = split(R[r][c] * M[r][c] * s)
__global__ __launch_bounds__(256) void k_wsplit(
    const float* __restrict__ R, const float* __restrict__ M,
    unsigned short* __restrict__ Ohi, unsigned short* __restrict__ Olo,
    int NR, int NC, int NCp, const float* __restrict__ scal, int scidx)
{
    __shared__ float T[64][65];
    const int nct = NCp >> 6;
    const int c0 = (blockIdx.x % nct) << 6;
    const int r0 = (blockIdx.x / nct) << 6;
    const float s = (scidx >= 0) ? scal[scidx] : 1.f;
    const int t = threadIdx.x;
    const int ir = t >> 2, ics = (t & 3) << 4;
#pragma unroll
    for (int i = 0; i < 16; ++i) {
        const int c = c0 + ics + i;
        float v = 0.f;
        if (c < NC) {
            const size_t idx = (size_t)(r0 + ir) * NC + c;
            v = R[idx] * M[idx] * s;
        }
        T[ir][ics + i] = v;
    }
    __syncthreads();
    const int oc = t >> 2, ors = (t & 3) << 4;
    unsigned short hb[16], lb[16];
#pragma unroll
    for (int i = 0; i < 16; ++i) split2(T[ors + i][oc], hb[i], lb[i]);
    const size_t base = (size_t)(c0 + oc) * NR + r0 + ors;
    uint4 v;
    v.x = hb[0] | ((unsigned)hb[1] << 16);  v.y = hb[2] | ((unsigned)hb[3] << 16);
    v.z = hb[4] | ((unsigned)hb[5] << 16);  v.w = hb[6] | ((unsigned)hb[7] << 16);
    *(uint4*)(Ohi + base) = v;
    v.x = hb[8] | ((unsigned)hb[9] << 16);  v.y = hb[10] | ((unsigned)hb[11] << 16);
    v.z = hb[12] | ((unsigned)hb[13] << 16); v.w = hb[14] | ((unsigned)hb[15] << 16);
    *(uint4*)(Ohi + base + 8) = v;
    v.x = lb[0] | ((unsigned)lb[1] << 16);  v.y = lb[2] | ((unsigned)lb[3] << 16);
    v.z = lb[4] | ((unsigned)lb[5] << 16);  v.w = lb[6] | ((unsigned)lb[7] << 16);
    *(uint4*)(Olo + base) = v;
    v.x = lb[8] | ((unsigned)lb[9] << 16);  v.y = lb[10] | ((unsigned)lb[11] << 16);
    v.z = lb[12] | ((unsigned)lb[13] << 16); v.w = lb[14] | ((unsigned)lb[15] << 16);
    *(uint4*)(Olo + base + 8) = v;
}

// drive = x @ W_IH + BH
__global__ __launch_bounds__(1024) void k_drive_mfma(
    const float* __restrict__ x,
    const unsigned short* __restrict__ WIHThi, const unsigned short* __restrict__ WIHTlo,
    const float* __restrict__ BH, float* __restrict__ drive)
{
    __shared__ char lds[32768];
    f32x4 acc;
    const int row0 = (blockIdx.x >> 5) * 64, col0 = (blockIdx.x & 31) * 64;
    tile64_gemm(x, ID, row0, WIHThi, WIHTlo, ID, col0, ID, lds, acc);
    const int lane = threadIdx.x & 63, w = threadIdx.x >> 6;
    const int gc = col0 + (w & 3) * 16 + (lane & 15);
    const int gr0 = row0 + (w >> 2) * 16 + ((lane >> 4) << 2);
    const float bh = BH[gc];
#pragma unroll
    for (int r = 0; r < 4; ++r)
        drive[(size_t)(gr0 + r) * HDm + gc] = acc[r] + bh;
}

// ---------------------------------------------------------------------------
// Cooperative loop kernel: 256 blocks x 1024 threads, custom grid barrier
// ---------------------------------------------------------------------------
__global__ __launch_bounds__(1024) void k_crp_loop(
    const unsigned short* __restrict__ WHThi, const unsigned short* __restrict__ WHTlo,
    const unsigned short* __restrict__ WHLThi, const unsigned short* __restrict__ WHLTlo,
    const float* __restrict__ drive, const float* __restrict__ BL,
    float* Ha, float* Hb, float* logits,
    int* active, int* nact, const float* scal, float* out, int* bar)
{
    __shared__ char lds[49152];
    __shared__ int s_any;
    const int bid = blockIdx.x, tid = threadIdx.x;
    const float gamma2 = 2.f * scal[3];
    float* Hs = Ha;
    float* Hn = Hb;
    int bc = 0;                                   // barrier index

    for (int t = 1; t <= TMAXc; ++t) {
        // ---- P1: Hn = select(active, LeakyReLU(Hs@W_H + drive), Hs) ----
        {
            const int row0 = (bid >> 5) * 64, col0 = (bid & 31) * 64;
            if (tid < 64) {
                int a = active[row0 + tid];
                unsigned long long bl = __ballot(a != 0);
                if (tid == 0) s_any = (bl != 0ull);
            }
            __syncthreads();
            if (s_any) {
                f32x4 acc;
                tile64_gemm(Hs, HDm, row0, WHThi, WHTlo, HDm, col0, HDm, lds, acc);
                const int lane = tid & 63, w = tid >> 6;
                const int gc = col0 + (w & 3) * 16 + (lane & 15);
                const int gr0 = row0 + (w >> 2) * 16 + ((lane >> 4) << 2);
#pragma unroll
                for (int r = 0; r < 4; ++r) {
                    const int gr = gr0 + r;
                    const float pre = acc[r] + drive[(size_t)gr * HDm + gc];
                    const float av = pre >= 0.f ? pre : ALPHAc * pre;
                    const int act = active[gr];
                    Hn[(size_t)gr * HDm + gc] = act ? av : Hs[(size_t)gr * HDm + gc];
                }
            }
        }
        gbar(bar, bc++);

        // ---- P2: logits = Hn @ W_HL + BL  (skip fully-frozen row-tiles) ----
        {
            const int row0 = (bid >> 4) * 32, col0 = (bid & 15) * 64;
            __syncthreads();
            if (tid < 64) {
                int a = (tid < 32) ? active[row0 + tid] : 0;
                unsigned long long bl = __ballot(a != 0);
                if (tid == 0) s_any = (bl != 0ull);
            }
            __syncthreads();
            if (s_any) {
                f32x4 acc;
                int s, p;
                tile32_gemm_ks(Hn, row0, WHLThi, WHLTlo, col0, lds, acc, s, p);
                const int lane = tid & 63;
                f32x4* red = (f32x4*)lds;
                __syncthreads();
                if (p == 1) red[s * 64 + lane] = acc;
                __syncthreads();
                if (p == 0) {
                    f32x4 o = red[s * 64 + lane];
                    const int gc = col0 + (s & 3) * 16 + (lane & 15);
                    if (gc < LD) {
                        const int gr0 = row0 + (s >> 2) * 16 + ((lane >> 4) << 2);
                        const float blv = BL[gc];
#pragma unroll
                        for (int r = 0; r < 4; ++r)
                            logits[(size_t)(gr0 + r) * LD + gc] = acc[r] + o[r] + blv;
                    }
                }
            }
        }
        gbar(bar, bc++);

        // ---- P3: per-row certification (one wave per row) ----
        {
            const int lane = tid & 63;
            const int wave = bid * 16 + (tid >> 6);
            if (wave < BN && active[wave]) {
                const int b = wave;
                const float4* hn4 = (const float4*)(Hn + (size_t)b * HDm);
                const float4* hs4 = (const float4*)(Hs + (size_t)b * HDm);
                float dh = 0.f;
                for (int i = lane; i < HDm / 4; i += 64) {
                    float4 a = hn4[i], c = hs4[i];
                    dh = fmaxf(dh, fmaxf(fmaxf(fabsf(a.x - c.x), fabsf(a.y - c.y)),
                                         fmaxf(fabsf(a.z - c.z), fabsf(a.w - c.w))));
                }
#pragma unroll
                for (int off = 1; off < 64; off <<= 1)
                    dh = fmaxf(dh, __shfl_xor(dh, off));
                const float4* lr4 = (const float4*)(logits + (size_t)b * LD);
                float m1 = -3.4e38f, m2 = -3.4e38f;
                for (int i = lane; i < LD / 4; i += 64) {
                    float4 v4 = lr4[i];
#pragma unroll
                    for (int e = 0; e < 4; ++e) {
                        float v = (&v4.x)[e];
                        if (v > m1) { m2 = m1; m1 = v; }
                        else m2 = fmaxf(m2, v);
                    }
                }
#pragma unroll
                for (int off = 1; off < 64; off <<= 1) {
                    float o1 = __shfl_xor(m1, off);
                    float o2 = __shfl_xor(m2, off);
                    if (o1 > m1) { m2 = fmaxf(m1, o2); m1 = o1; }
                    else m2 = fmaxf(m2, o1);
                }
                const bool newly = (m1 - m2) > gamma2 * dh;
                if (newly) {
                    float4* o4 = (float4*)(out + (size_t)b * LD);
                    for (int i = lane; i < LD / 4; i += 64) o4[i] = lr4[i];
                    if (lane == 0) active[b] = 0;
                } else if (lane == 0) {
                    atomicAdd(&nact[t], 1);
                }
            }
        }
        gbar(bar, bc++);
        const int remaining = __hip_atomic_load(&nact[t], __ATOMIC_RELAXED, __HIP_MEMORY_SCOPE_AGENT);
        float* tmp = Hs; Hs = Hn; Hn = tmp;
        if (remaining == 0) break;
    }

    // ---- never-certified rows take last logits ----
    {
        const int lane = tid & 63;
        const int wave = bid * 16 + (tid >> 6);
        if (wave < BN && active[wave]) {
            const float4* lr4 = (const float4*)(logits + (size_t)wave * LD);
            float4* o4 = (float4*)(out + (size_t)wave * LD);
            for (int i = lane; i < LD / 4; i += 64) o4[i] = lr4[i];
        }
    }
}

// ---------------------------------------------------------------------------
extern "C" void kernel_launch(void* const* d_in, const int* in_sizes, int n_in,
                              void* d_out, int out_size, void* d_ws, size_t ws_size,
                              hipStream_t stream)
{
    const float* x   = (const float*)d_in[0];
    const float* RIH = (const float*)d_in[1];
    const float* RH  = (const float*)d_in[2];
    const float* RHL = (const float*)d_in[3];
    const float* BH  = (const float*)d_in[4];
    const float* BL  = (const float*)d_in[5];
    const float* MIH = (const float*)d_in[6];
    const float* MH  = (const float*)d_in[7];
    const float* MHL = (const float*)d_in[8];
    float* out = (float*)d_out;
    char* w = (char*)d_ws;

    unsigned short* WHThi = (unsigned short*)(w);                 //  8 MB
    unsigned short* WHTlo = (unsigned short*)(w + 8388608);       //  8 MB
    unsigned short* WXhi  = (unsigned short*)(w + 16777216);      //  4 MB
    unsigned short* WXlo  = (unsigned short*)(w + 20971520);      //  4 MB
    float* drive  = (float*)(w + 25165824);                       //  4 MB
    float* Ha     = (float*)(w + 29360128);                       //  4 MB
    float* Hb     = (float*)(w + 33554432);                       //  4 MB
    float* logits = (float*)(w + 37748736);                       //  2 MB
    float* scal   = (float*)(w + 39796736);                       //  8 f
    int*   active = (int*)(w + 39796768);                         //  512 i
    int*   nact   = (int*)(w + 39798816);                         //  33 i
    int*   bar    = (int*)(w + 39798952);                         //  69 i

    k_init<<<2, 256, 0, stream>>>(active, nact, scal, bar);
    k_colsum_wh<<<32, 1024, 0, stream>>>(RH, MH, scal);
    k_colsum_whl<<<16, 1024, 0, stream>>>(RHL, MHL, scal);
    k_scalars<<<1, 64, 0, stream>>>(scal);
    k_wsplit<<<512, 256, 0, stream>>>(RIH, MIH, WXhi, WXlo, ID, HDm, HDm, scal, -1);
    k_drive_mfma<<<256, 1024, 0, stream>>>(x, WXhi, WXlo, BH, drive);
    k_wsplit<<<1024, 256, 0, stream>>>(RH, MH, WHThi, WHTlo, HDm, HDm, HDm, scal, 2);
    k_wsplit<<<512, 256, 0, stream>>>(RHL, MHL, WXhi, WXlo, HDm, LD, 1024, scal, -1);
    hipMemsetAsync(Ha, 0, (size_t)BN * HDm * sizeof(float), stream);

    void* args[] = {(void*)&WHThi, (void*)&WHTlo, (void*)&WXhi, (void*)&WXlo,
                    (void*)&drive, (void*)&BL, (void*)&Ha, (void*)&Hb, (void*)&logits,
                    (void*)&active, (void*)&nact, (void*)&scal, (void*)&out, (void*)&bar};
    hipLaunchCooperativeKernel(reinterpret_cast<void*>(k_crp_loop),
                               dim3(256), dim3(1024), args, 0, stream);
}

// Round 6
// 2495.961 us; speedup vs baseline: 5.4443x; 5.4443x over previous
//
#include <hip/hip_runtime.h>

typedef __attribute__((ext_vector_type(8))) short short8;
typedef __attribute__((ext_vector_type(4))) float f32x4;

static constexpr int BN    = 512;
static constexpr int ID    = 1024;
static constexpr int HDm   = 2048;
static constexpr int LD    = 1000;
static constexpr int TMAXc = 32;
static constexpr float ALPHAc = 0.05f;

// ---------------- bf16 split helpers (x ~= hi + lo, each bf16) ----------------
__device__ __forceinline__ unsigned short f2bf(float x) {
    unsigned u = __float_as_uint(x);
    u += 0x7fffu + ((u >> 16) & 1u);           // RNE
    return (unsigned short)(u >> 16);
}
__device__ __forceinline__ float bf2f(unsigned short h) {
    return __uint_as_float(((unsigned)h) << 16);
}
__device__ __forceinline__ void split2(float x, unsigned short& hi, unsigned short& lo) {
    hi = f2bf(x);
    lo = f2bf(x - bf2f(hi));
}

// ---------------------------------------------------------------------------
// Grid barrier, 256 blocks. Tree arrival (16 leaves + root) with RELAXED
// atomics; poll is RELAXED (no per-poll cache invalidate — round-5's bug);
// exactly ONE release fence (wbL2) before arrival and ONE acquire fence
// (invL1/L2) after release is observed. bar: [0..63] leaves[slot][16],
// [64..67] root[slot], [68] release, [80] n_rem.
// ---------------------------------------------------------------------------
__device__ __forceinline__ void gbar(int* bar, int idx)
{
    __syncthreads();
    if (threadIdx.x == 0) {
        __builtin_amdgcn_fence(__ATOMIC_RELEASE, "agent");   // flush our dirty L2 lines
        const int slot = idx & 3;
        int a = __hip_atomic_fetch_add(bar + slot * 16 + (blockIdx.x & 15), 1,
                                       __ATOMIC_RELAXED, __HIP_MEMORY_SCOPE_AGENT);
        if (a == 15) {
            int r = __hip_atomic_fetch_add(bar + 64 + slot, 1,
                                           __ATOMIC_RELAXED, __HIP_MEMORY_SCOPE_AGENT);
            if (r == 15) {
#pragma unroll
                for (int g = 0; g < 16; ++g)
                    __hip_atomic_store(bar + slot * 16 + g, 0, __ATOMIC_RELAXED, __HIP_MEMORY_SCOPE_AGENT);
                __hip_atomic_store(bar + 64 + slot, 0, __ATOMIC_RELAXED, __HIP_MEMORY_SCOPE_AGENT);
                __hip_atomic_fetch_add(bar + 68, 1, __ATOMIC_RELAXED, __HIP_MEMORY_SCOPE_AGENT);
            }
        }
        while (__hip_atomic_load(bar + 68, __ATOMIC_RELAXED, __HIP_MEMORY_SCOPE_AGENT) < idx + 1)
            __builtin_amdgcn_s_sleep(4);
        __builtin_amdgcn_fence(__ATOMIC_ACQUIRE, "agent");   // see others' stores
    }
    __syncthreads();
}

// ---------------------------------------------------------------------------
// 64x64 tile, 1024 threads (16 waves, one 16x16 C-fragment each), K-step 64,
// 2-deep register prefetch, split-bf16 3-term MFMA (~fp32 accuracy).
// ---------------------------------------------------------------------------
__device__ __forceinline__ void tile64_gemm(
    const float* __restrict__ A, int lda, int row0,
    const unsigned short* __restrict__ BThi, const unsigned short* __restrict__ BTlo,
    int ldk, int col0, int K, char* lds, f32x4& acc)
{
    char* Ah = lds;
    char* Al = lds + 8192;
    char* Bh = lds + 16384;
    char* Bl = lds + 24576;
    const int t = threadIdx.x, lane = t & 63, w = t >> 6;
    const int wrow = w >> 2, wcol = w & 3;
    f32x4 z = {0.f, 0.f, 0.f, 0.f};
    acc = z;

    const int ar = t >> 4, ac = (t & 15) << 2;
    const int br = t >> 4, bc = (t & 15) << 2;
    const float* Ap = A + (size_t)(row0 + ar) * lda + ac;
    const unsigned short* Bhp = BThi + (size_t)(col0 + br) * ldk + bc;
    const unsigned short* Blp = BTlo + (size_t)(col0 + br) * ldk + bc;
    const int asb = (ar * 128 + ac * 2) ^ ((ar & 7) << 4);
    const int bsb = (br * 128 + bc * 2) ^ ((br & 7) << 4);
    const int colr = wcol * 16 + (lane & 15);
    const int arow = wrow * 16 + (lane & 15);
    const int bb0 = colr * 128, ab0 = arow * 128;
    const int bxor = (colr & 7) << 4, axor = (arow & 7) << 4;
    const int kb0 = (lane >> 4) << 4;

    float4 av0 = *(const float4*)(Ap);
    uint2  bh0 = *(const uint2*)(Bhp);
    uint2  bl0 = *(const uint2*)(Blp);
    float4 av1 = *(const float4*)(Ap + 64);
    uint2  bh1 = *(const uint2*)(Bhp + 64);
    uint2  bl1 = *(const uint2*)(Blp + 64);

    for (int k0 = 0; k0 < K; k0 += 64) {
        unsigned short h0, h1, h2, h3, l0, l1, l2, l3;
        split2(av0.x, h0, l0); split2(av0.y, h1, l1);
        split2(av0.z, h2, l2); split2(av0.w, h3, l3);
        uint2 ahp = make_uint2((unsigned)h0 | ((unsigned)h1 << 16),
                               (unsigned)h2 | ((unsigned)h3 << 16));
        uint2 alp = make_uint2((unsigned)l0 | ((unsigned)l1 << 16),
                               (unsigned)l2 | ((unsigned)l3 << 16));
        uint2 bhw = bh0, blw = bl0;
        __syncthreads();
        *(uint2*)(Ah + asb) = ahp;
        *(uint2*)(Al + asb) = alp;
        *(uint2*)(Bh + bsb) = bhw;
        *(uint2*)(Bl + bsb) = blw;
        av0 = av1; bh0 = bh1; bl0 = bl1;
        if (k0 + 128 < K) {
            av1 = *(const float4*)(Ap + k0 + 128);
            bh1 = *(const uint2*)(Bhp + k0 + 128);
            bl1 = *(const uint2*)(Blp + k0 + 128);
        }
        __syncthreads();
#pragma unroll
        for (int ks = 0; ks < 2; ++ks) {
            const int kb = ks * 64 + kb0;
            short8 bh = *(const short8*)(Bh + ((bb0 + kb) ^ bxor));
            short8 bl = *(const short8*)(Bl + ((bb0 + kb) ^ bxor));
            short8 ah = *(const short8*)(Ah + ((ab0 + kb) ^ axor));
            short8 al = *(const short8*)(Al + ((ab0 + kb) ^ axor));
            acc = __builtin_amdgcn_mfma_f32_16x16x32_bf16(ah, bh, acc, 0, 0, 0);
            acc = __builtin_amdgcn_mfma_f32_16x16x32_bf16(al, bh, acc, 0, 0, 0);
            acc = __builtin_amdgcn_mfma_f32_16x16x32_bf16(ah, bl, acc, 0, 0, 0);
        }
    }
}

// ---------------------------------------------------------------------------
// 32x64 tile, K=2048, 16 waves = 8 C-fragments x 2 K-halves, 2-deep prefetch.
// ---------------------------------------------------------------------------
__device__ __forceinline__ void tile32_gemm_ks(
    const float* __restrict__ A, int row0,
    const unsigned short* __restrict__ BThi, const unsigned short* __restrict__ BTlo,
    int col0, char* lds, f32x4& acc, int& s_out, int& p_out)
{
    char* Ah = lds;
    char* Al = lds + 8192;
    char* Bh = lds + 16384;
    char* Bl = lds + 32768;
    const int t = threadIdx.x, lane = t & 63, w = t >> 6;
    const int s = w & 7, p = w >> 3;
    s_out = s; p_out = p;
    const int mrow = s >> 2, wcol = s & 3;
    f32x4 z = {0.f, 0.f, 0.f, 0.f};
    acc = z;

    const int ar = t >> 5, ac = (t & 31) << 2;
    const int br = t >> 4, bc = (t & 15) << 3;
    const float* Ap = A + (size_t)(row0 + ar) * HDm + ac;
    const unsigned short* Bhp = BThi + (size_t)(col0 + br) * HDm + bc;
    const unsigned short* Blp = BTlo + (size_t)(col0 + br) * HDm + bc;
    const int asb = (ar * 256 + ac * 2) ^ ((ar & 15) << 4);
    const int bsb = (br * 256 + bc * 2) ^ ((br & 15) << 4);
    const int colr = wcol * 16 + (lane & 15);
    const int arow = mrow * 16 + (lane & 15);
    const int bb0 = colr * 256, ab0 = arow * 256;
    const int bxor = (colr & 15) << 4, axor = (arow & 15) << 4;
    const int kc = p * 128;
    const int kb0 = (lane >> 4) << 4;

    float4 av0 = *(const float4*)(Ap);
    uint4  bh0 = *(const uint4*)(Bhp);
    uint4  bl0 = *(const uint4*)(Blp);
    float4 av1 = *(const float4*)(Ap + 128);
    uint4  bh1 = *(const uint4*)(Bhp + 128);
    uint4  bl1 = *(const uint4*)(Blp + 128);

    for (int k0 = 0; k0 < HDm; k0 += 128) {
        unsigned short h0, h1, h2, h3, l0, l1, l2, l3;
        split2(av0.x, h0, l0); split2(av0.y, h1, l1);
        split2(av0.z, h2, l2); split2(av0.w, h3, l3);
        uint2 ahp = make_uint2((unsigned)h0 | ((unsigned)h1 << 16),
                               (unsigned)h2 | ((unsigned)h3 << 16));
        uint2 alp = make_uint2((unsigned)l0 | ((unsigned)l1 << 16),
                               (unsigned)l2 | ((unsigned)l3 << 16));
        uint4 bhw = bh0, blw = bl0;
        __syncthreads();
        *(uint2*)(Ah + asb) = ahp;
        *(uint2*)(Al + asb) = alp;
        *(uint4*)(Bh + bsb) = bhw;
        *(uint4*)(Bl + bsb) = blw;
        av0 = av1; bh0 = bh1; bl0 = bl1;
        if (k0 + 256 < HDm) {
            av1 = *(const float4*)(Ap + k0 + 256);
            bh1 = *(const uint4*)(Bhp + k0 + 256);
            bl1 = *(const uint4*)(Blp + k0 + 256);
        }
        __syncthreads();
#pragma unroll
        for (int ks = 0; ks < 2; ++ks) {
            const int kb = kc + ks * 64 + kb0;
            short8 bh = *(const short8*)(Bh + ((bb0 + kb) ^ bxor));
            short8 bl = *(const short8*)(Bl + ((bb0 + kb) ^ bxor));
            short8 ah = *(const short8*)(Ah + ((ab0 + kb) ^ axor));
            short8 al = *(const short8*)(Al + ((ab0 + kb) ^ axor));
            acc = __builtin_amdgcn_mfma_f32_16x16x32_bf16(ah, bh, acc, 0, 0, 0);
            acc = __builtin_amdgcn_mfma_f32_16x16x32_bf16(al, bh, acc, 0, 0, 0);
            acc = __builtin_amdgcn_mfma_f32_16x16x32_bf16(ah, bl, acc, 0, 0, 0);
        }
    }
}

// ---------------------------------------------------------------------------
// Prep kernels
// ---------------------------------------------------------------------------
__global__ void k_init(int* active, float* scal, int* bar)
{
    int i = blockIdx.x * blockDim.x + threadIdx.x;
    if (i < BN) active[i] = 1;
    if (i < 8) scal[i] = 0.f;
    if (i < 96) bar[i] = (i == 80) ? BN : 0;
}

__global__ __launch_bounds__(1024) void k_colsum_wh(const float* __restrict__ RH,
                                                    const float* __restrict__ MH,
                                                    float* scal)
{
    const int col = blockIdx.x * 64 + (threadIdx.x & 63);
    const int rs  = threadIdx.x >> 6;
    float s = 0.f;
    for (int i = rs; i < HDm; i += 16)
        s += fabsf(RH[(size_t)i * HDm + col] * MH[(size_t)i * HDm + col]);
    __shared__ float red[16][64];
    red[rs][threadIdx.x & 63] = s;
    __syncthreads();
    if (threadIdx.x < 64) {
        float c = 0.f;
#pragma unroll
        for (int j = 0; j < 16; ++j) c += red[j][threadIdx.x];
#pragma unroll
        for (int off = 1; off < 64; off <<= 1) c = fmaxf(c, __shfl_xor(c, off));
        if (threadIdx.x == 0)
            atomicMax((unsigned int*)&scal[0], __float_as_uint(c));
    }
}

__global__ __launch_bounds__(1024) void k_colsum_whl(const float* __restrict__ RHL,
                                                     const float* __restrict__ MHL,
                                                     float* scal)
{
    const int col = blockIdx.x * 64 + (threadIdx.x & 63);
    const int rs  = threadIdx.x >> 6;
    float s = 0.f;
    if (col < LD) {
        for (int i = rs; i < HDm; i += 16)
            s += fabsf(RHL[(size_t)i * LD + col] * MHL[(size_t)i * LD + col]);
    }
    __shared__ float red[16][64];
    red[rs][threadIdx.x & 63] = s;
    __syncthreads();
    if (threadIdx.x < 64) {
        float c = 0.f;
#pragma unroll
        for (int j = 0; j < 16; ++j) c += red[j][threadIdx.x];
#pragma unroll
        for (int off = 1; off < 64; off <<= 1) c = fmaxf(c, __shfl_xor(c, off));
        if (threadIdx.x == 0)
            atomicMax((unsigned int*)&scal[1], __float_as_uint(c));
    }
}

__global__ void k_scalars(float* scal)
{
    if (threadIdx.x == 0 && blockIdx.x == 0) {
        scal[2] = 0.95f / fmaxf(scal[0], 1e-8f);
        scal[3] = scal[1] * 19.f;
    }
}

__global__ __launch_bounds__(256) void k_wsplit(
    const float* __restrict__ R, const float* __restrict__ M,
    unsigned short* __restrict__ Ohi, unsigned short* __restrict__ Olo,
    int NR, int NC, int NCp, const float* __restrict__ scal, int scidx)
{
    __shared__ float T[64][65];
    const int nct = NCp >> 6;
    const int c0 = (blockIdx.x % nct) << 6;
    const int r0 = (blockIdx.x / nct) << 6;
    const float s = (scidx >= 0) ? scal[scidx] : 1.f;
    const int t = threadIdx.x;
    const int ir = t >> 2, ics = (t & 3) << 4;
#pragma unroll
    for (int i = 0; i < 16; ++i) {
        const int c = c0 + ics + i;
        float v = 0.f;
        if (c < NC) {
            const size_t idx = (size_t)(r0 + ir) * NC + c;
            v = R[idx] * M[idx] * s;
        }
        T[ir][ics + i] = v;
    }
    __syncthreads();
    const int oc = t >> 2, ors = (t & 3) << 4;
    unsigned short hb[16], lb[16];
#pragma unroll
    for (int i = 0; i < 16; ++i) split2(T[ors + i][oc], hb[i], lb[i]);
    const size_t base = (size_t)(c0 + oc) * NR + r0 + ors;
    uint4 v;
    v.x = hb[0] | ((unsigned)hb[1] << 16);  v.y = hb[2] | ((unsigned)hb[3] << 16);
    v.z = hb[4] | ((unsigned)hb[5] << 16);  v.w = hb[6] | ((unsigned)hb[7] << 16);
    *(uint4*)(Ohi + base) = v;
    v.x = hb[8] | ((unsigned)hb[9] << 16);  v.y = hb[10] | ((unsigned)hb[11] << 16);
    v.z = hb[12] | ((unsigned)hb[13] << 16); v.w = hb[14] | ((unsigned)hb[15] << 16);
    *(uint4*)(Ohi + base + 8) = v;
    v.x = lb[0] | ((unsigned)lb[1] << 16);  v.y = lb[2] | ((unsigned)lb[3] << 16);
    v.z = lb[4] | ((unsigned)lb[5] << 16);  v.w = lb[6] | ((unsigned)lb[7] << 16);
    *(uint4*)(Olo + base) = v;
    v.x = lb[8] | ((unsigned)lb[9] << 16);  v.y = lb[10] | ((unsigned)lb[11] << 16);
    v.z = lb[12] | ((unsigned)lb[13] << 16); v.w = lb[14] | ((unsigned)lb[15] << 16);
    *(uint4*)(Olo + base + 8) = v;
}

__global__ __launch_bounds__(1024) void k_drive_mfma(
    const float* __restrict__ x,
    const unsigned short* __restrict__ WIHThi, const unsigned short* __restrict__ WIHTlo,
    const float* __restrict__ BH, float* __restrict__ drive)
{
    __shared__ char lds[32768];
    f32x4 acc;
    const int row0 = (blockIdx.x >> 5) * 64, col0 = (blockIdx.x & 31) * 64;
    tile64_gemm(x, ID, row0, WIHThi, WIHTlo, ID, col0, ID, lds, acc);
    const int lane = threadIdx.x & 63, w = threadIdx.x >> 6;
    const int gc = col0 + (w & 3) * 16 + (lane & 15);
    const int gr0 = row0 + (w >> 2) * 16 + ((lane >> 4) << 2);
    const float bh = BH[gc];
#pragma unroll
    for (int r = 0; r < 4; ++r)
        drive[(size_t)(gr0 + r) * HDm + gc] = acc[r] + bh;
}

// ---------------------------------------------------------------------------
// Loop kernel: 256 blocks x 1024 threads, 2 barriers/step.
// Per step: [finalize(t-1); P1 + dH-partials] A [exit?] [P2 + top2-partials] B
// Certification is finalized idempotently by every block for its own rows.
// ---------------------------------------------------------------------------
__global__ __launch_bounds__(1024) void k_crp_loop(
    const unsigned short* __restrict__ WHThi, const unsigned short* __restrict__ WHTlo,
    const unsigned short* __restrict__ WHLThi, const unsigned short* __restrict__ WHLTlo,
    const float* __restrict__ drive, const float* __restrict__ BL,
    float* Ha, float* Hb, float* logits,
    int* active, const float* scal, float* out, int* bar,
    float* dhp, float* m1p, float* m2p)
{
    __shared__ char lds[49152];
    __shared__ int s_any;
    const int bid = blockIdx.x, tid = threadIdx.x;
    const float gamma2 = 2.f * scal[3];
    int* nrem = bar + 80;
    float* Hs = Ha;
    float* Hn = Hb;
    int bc = 0;

    const int m1t = bid >> 5;                 // P1 row-tile (64 rows)
    const int row0m = m1t << 6;

    for (int t = 1; t <= TMAXc; ++t) {
        // ---- finalize(t-1): certify rows of our tile from partials ----
        if (t > 1) {
            const int rl = tid >> 4, j = tid & 15;
            const int r = row0m + rl;
            const int act = active[r];
            float dh = fmaxf(dhp[(size_t)r * 32 + j], dhp[(size_t)r * 32 + 16 + j]);
            float M1 = m1p[(size_t)r * 16 + j], M2 = m2p[(size_t)r * 16 + j];
#pragma unroll
            for (int off = 1; off < 16; off <<= 1) {
                dh = fmaxf(dh, __shfl_xor(dh, off));
                float o1 = __shfl_xor(M1, off), o2 = __shfl_xor(M2, off);
                if (o1 > M1) { M2 = fmaxf(M1, o2); M1 = o1; }
                else M2 = fmaxf(M2, o1);
            }
            int* snew = (int*)(lds + 4096);
            if (j == 0) {
                int nw = act && ((M1 - M2) > gamma2 * dh);
                snew[rl] = nw;
                if (nw) active[r] = 0;
            }
            __syncthreads();
            if ((bid & 31) == 0) {
                int cnt = 0;
                for (int rl2 = 0; rl2 < 64; ++rl2) {
                    if (snew[rl2]) {
                        ++cnt;
                        const float* lr = logits + (size_t)(row0m + rl2) * LD;
                        float* orow = out + (size_t)(row0m + rl2) * LD;
                        for (int jj = tid; jj < LD; jj += 1024) orow[jj] = lr[jj];
                    }
                }
                if (tid == 0 && cnt)
                    __hip_atomic_fetch_add(nrem, -cnt, __ATOMIC_RELAXED, __HIP_MEMORY_SCOPE_AGENT);
            }
            __syncthreads();
        }

        // ---- P1: Hn = select(active, LeakyReLU(Hs@W_H + drive), Hs) + dH partials ----
        {
            const int row0 = row0m, col0 = (bid & 31) * 64;
            if (tid < 64) {
                int a = active[row0 + tid];
                unsigned long long bl = __ballot(a != 0);
                if (tid == 0) s_any = (bl != 0ull);
            }
            __syncthreads();
            if (s_any) {
                f32x4 acc;
                tile64_gemm(Hs, HDm, row0, WHThi, WHTlo, HDm, col0, HDm, lds, acc);
                const int lane = tid & 63, w = tid >> 6;
                const int gc = col0 + (w & 3) * 16 + (lane & 15);
                const int gr0 = row0 + (w >> 2) * 16 + ((lane >> 4) << 2);
                float dh4[4];
#pragma unroll
                for (int r = 0; r < 4; ++r) {
                    const int gr = gr0 + r;
                    const float old = Hs[(size_t)gr * HDm + gc];
                    const float pre = acc[r] + drive[(size_t)gr * HDm + gc];
                    const float av = pre >= 0.f ? pre : ALPHAc * pre;
                    const int act = active[gr];
                    const float nv = act ? av : old;
                    Hn[(size_t)gr * HDm + gc] = nv;
                    dh4[r] = fabsf(nv - old);
                }
#pragma unroll
                for (int off = 1; off < 16; off <<= 1)
#pragma unroll
                    for (int r = 0; r < 4; ++r)
                        dh4[r] = fmaxf(dh4[r], __shfl_xor(dh4[r], off));
                __syncthreads();            // tile64 LDS reads done before reuse
                float (*sdh)[4] = (float(*)[4])lds;
                if ((lane & 15) == 0) {
                    const int rl0 = (w >> 2) * 16 + ((lane >> 4) << 2);
#pragma unroll
                    for (int r = 0; r < 4; ++r) sdh[rl0 + r][w & 3] = dh4[r];
                }
                __syncthreads();
                if (tid < 64) {
                    float d = fmaxf(fmaxf(sdh[tid][0], sdh[tid][1]),
                                    fmaxf(sdh[tid][2], sdh[tid][3]));
                    dhp[(size_t)(row0 + tid) * 32 + (bid & 31)] = d;
                }
            }
        }
        gbar(bar, bc++);

        if (__hip_atomic_load(nrem, __ATOMIC_RELAXED, __HIP_MEMORY_SCOPE_AGENT) == 0)
            break;

        // ---- P2: logits = Hn @ W_HL + BL + top2 partials ----
        {
            const int row0 = (bid >> 4) * 32, col0 = (bid & 15) * 64;
            __syncthreads();
            if (tid < 64) {
                int a = (tid < 32) ? active[row0 + tid] : 0;
                unsigned long long bl = __ballot(a != 0);
                if (tid == 0) s_any = (bl != 0ull);
            }
            __syncthreads();
            if (s_any) {
                f32x4 acc;
                int s, p;
                tile32_gemm_ks(Hn, row0, WHLThi, WHLTlo, col0, lds, acc, s, p);
                const int lane = tid & 63;
                f32x4* red = (f32x4*)lds;
                float (*st1)[4] = (float(*)[4])(lds + 36864);
                float (*st2)[4] = (float(*)[4])(lds + 37888);
                __syncthreads();
                if (p == 1) red[s * 64 + lane] = acc;
                __syncthreads();
                if (p == 0) {
                    f32x4 o = red[s * 64 + lane];
                    const int gc = col0 + (s & 3) * 16 + (lane & 15);
                    const int gr0 = row0 + (s >> 2) * 16 + ((lane >> 4) << 2);
                    const bool okc = gc < LD;
                    const float blv = okc ? BL[gc] : 0.f;
                    float m1a[4], m2a[4];
#pragma unroll
                    for (int r = 0; r < 4; ++r) {
                        const float v = acc[r] + o[r] + blv;
                        if (okc) logits[(size_t)(gr0 + r) * LD + gc] = v;
                        m1a[r] = okc ? v : -3.4e38f;
                        m2a[r] = -3.4e38f;
                    }
#pragma unroll
                    for (int off = 1; off < 16; off <<= 1) {
#pragma unroll
                        for (int r = 0; r < 4; ++r) {
                            float o1 = __shfl_xor(m1a[r], off);
                            float o2 = __shfl_xor(m2a[r], off);
                            if (o1 > m1a[r]) { m2a[r] = fmaxf(m1a[r], o2); m1a[r] = o1; }
                            else m2a[r] = fmaxf(m2a[r], o1);
                        }
                    }
                    if ((lane & 15) == 0) {
                        const int rl0 = (s >> 2) * 16 + ((lane >> 4) << 2);
#pragma unroll
                        for (int r = 0; r < 4; ++r) {
                            st1[rl0 + r][s & 3] = m1a[r];
                            st2[rl0 + r][s & 3] = m2a[r];
                        }
                    }
                }
                __syncthreads();
                if (tid < 32) {
                    float M1 = st1[tid][0], M2 = st2[tid][0];
#pragma unroll
                    for (int g = 1; g < 4; ++g) {
                        float o1 = st1[tid][g], o2 = st2[tid][g];
                        if (o1 > M1) { M2 = fmaxf(M1, o2); M1 = o1; }
                        else M2 = fmaxf(M2, o1);
                    }
                    m1p[(size_t)(row0 + tid) * 16 + (bid & 15)] = M1;
                    m2p[(size_t)(row0 + tid) * 16 + (bid & 15)] = M2;
                }
            }
        }
        gbar(bar, bc++);
        float* tmp = Hs; Hs = Hn; Hn = tmp;
    }

    // ---- rows never certified (or certified exactly at TMAX) take last logits ----
    if ((bid & 31) == 0) {
        for (int rl = 0; rl < 64; ++rl) {
            if (active[row0m + rl]) {
                const float* lr = logits + (size_t)(row0m + rl) * LD;
                float* orow = out + (size_t)(row0m + rl) * LD;
                for (int jj = tid; jj < LD; jj += 1024) orow[jj] = lr[jj];
            }
        }
    }
}

// ---------------------------------------------------------------------------
extern "C" void kernel_launch(void* const* d_in, const int* in_sizes, int n_in,
                              void* d_out, int out_size, void* d_ws, size_t ws_size,
                              hipStream_t stream)
{
    const float* x   = (const float*)d_in[0];
    const float* RIH = (const float*)d_in[1];
    const float* RH  = (const float*)d_in[2];
    const float* RHL = (const float*)d_in[3];
    const float* BH  = (const float*)d_in[4];
    const float* BL  = (const float*)d_in[5];
    const float* MIH = (const float*)d_in[6];
    const float* MH  = (const float*)d_in[7];
    const float* MHL = (const float*)d_in[8];
    float* out = (float*)d_out;
    char* w = (char*)d_ws;

    unsigned short* WHThi = (unsigned short*)(w);                 //  8 MB
    unsigned short* WHTlo = (unsigned short*)(w + 8388608);       //  8 MB
    unsigned short* WXhi  = (unsigned short*)(w + 16777216);      //  4 MB
    unsigned short* WXlo  = (unsigned short*)(w + 20971520);      //  4 MB
    float* drive  = (float*)(w + 25165824);                       //  4 MB
    float* Ha     = (float*)(w + 29360128);                       //  4 MB
    float* Hb     = (float*)(w + 33554432);                       //  4 MB
    float* logits = (float*)(w + 37748736);                       //  2 MB
    float* scal   = (float*)(w + 39796736);                       //  8 f
    int*   active = (int*)(w + 39796800);                         //  512 i
    int*   bar    = (int*)(w + 39798848);                         //  96 i (n_rem at +80)
    float* dhp    = (float*)(w + 39799296);                       //  512*32 f = 64 KB
    float* m1p    = (float*)(w + 39864832);                       //  512*16 f = 32 KB
    float* m2p    = (float*)(w + 39897600);                       //  32 KB  (end ~38.1 MiB)

    k_init<<<2, 256, 0, stream>>>(active, scal, bar);
    k_colsum_wh<<<32, 1024, 0, stream>>>(RH, MH, scal);
    k_colsum_whl<<<16, 1024, 0, stream>>>(RHL, MHL, scal);
    k_scalars<<<1, 64, 0, stream>>>(scal);
    k_wsplit<<<512, 256, 0, stream>>>(RIH, MIH, WXhi, WXlo, ID, HDm, HDm, scal, -1);
    k_drive_mfma<<<256, 1024, 0, stream>>>(x, WXhi, WXlo, BH, drive);
    k_wsplit<<<1024, 256, 0, stream>>>(RH, MH, WHThi, WHTlo, HDm, HDm, HDm, scal, 2);
    k_wsplit<<<512, 256, 0, stream>>>(RHL, MHL, WXhi, WXlo, HDm, LD, 1024, scal, -1);
    hipMemsetAsync(Ha, 0, (size_t)BN * HDm * sizeof(float), stream);

    void* args[] = {(void*)&WHThi, (void*)&WHTlo, (void*)&WXhi, (void*)&WXlo,
                    (void*)&drive, (void*)&BL, (void*)&Ha, (void*)&Hb, (void*)&logits,
                    (void*)&active, (void*)&scal, (void*)&out, (void*)&bar,
                    (void*)&dhp, (void*)&m1p, (void*)&m2p};
    hipLaunchCooperativeKernel(reinterpret_cast<void*>(k_crp_loop),
                               dim3(256), dim3(1024), args, 0, stream);
}

// Round 8
// 1966.244 us; speedup vs baseline: 6.9111x; 1.2694x over previous
//
#include <hip/hip_runtime.h>

typedef __attribute__((ext_vector_type(8))) short short8;
typedef __attribute__((ext_vector_type(4))) float f32x4;

static constexpr int BN    = 512;
static constexpr int ID    = 1024;
static constexpr int HDm   = 2048;
static constexpr int LD    = 1000;
static constexpr int TMAXc = 32;
static constexpr float ALPHAc = 0.05f;

// ---------------- bf16 split helpers (x ~= hi + lo, each bf16) ----------------
__device__ __forceinline__ unsigned short f2bf(float x) {
    unsigned u = __float_as_uint(x);
    u += 0x7fffu + ((u >> 16) & 1u);           // RNE
    return (unsigned short)(u >> 16);
}
__device__ __forceinline__ float bf2f(unsigned short h) {
    return __uint_as_float(((unsigned)h) << 16);
}
__device__ __forceinline__ void split2(float x, unsigned short& hi, unsigned short& lo) {
    hi = f2bf(x);
    lo = f2bf(x - bf2f(hi));
}

// ---------------------------------------------------------------------------
// 64x64 tile, 1024 threads (16 waves, one 16x16 C-fragment each), K-step 64,
// 2-deep register prefetch, split-bf16 3-term MFMA (~fp32 accuracy).
// LDS XOR swizzle: byte ^= (row&7)<<4.
// ---------------------------------------------------------------------------
__device__ __forceinline__ void tile64_gemm(
    const float* __restrict__ A, int lda, int row0,
    const unsigned short* __restrict__ BThi, const unsigned short* __restrict__ BTlo,
    int ldk, int col0, int K, char* lds, f32x4& acc)
{
    char* Ah = lds;
    char* Al = lds + 8192;
    char* Bh = lds + 16384;
    char* Bl = lds + 24576;
    const int t = threadIdx.x, lane = t & 63, w = t >> 6;
    const int wrow = w >> 2, wcol = w & 3;
    f32x4 z = {0.f, 0.f, 0.f, 0.f};
    acc = z;

    const int ar = t >> 4, ac = (t & 15) << 2;
    const int br = t >> 4, bc = (t & 15) << 2;
    const float* Ap = A + (size_t)(row0 + ar) * lda + ac;
    const unsigned short* Bhp = BThi + (size_t)(col0 + br) * ldk + bc;
    const unsigned short* Blp = BTlo + (size_t)(col0 + br) * ldk + bc;
    const int asb = (ar * 128 + ac * 2) ^ ((ar & 7) << 4);
    const int bsb = (br * 128 + bc * 2) ^ ((br & 7) << 4);
    const int colr = wcol * 16 + (lane & 15);
    const int arow = wrow * 16 + (lane & 15);
    const int bb0 = colr * 128, ab0 = arow * 128;
    const int bxor = (colr & 7) << 4, axor = (arow & 7) << 4;
    const int kb0 = (lane >> 4) << 4;

    float4 av0 = *(const float4*)(Ap);
    uint2  bh0 = *(const uint2*)(Bhp);
    uint2  bl0 = *(const uint2*)(Blp);
    float4 av1 = *(const float4*)(Ap + 64);
    uint2  bh1 = *(const uint2*)(Bhp + 64);
    uint2  bl1 = *(const uint2*)(Blp + 64);

    for (int k0 = 0; k0 < K; k0 += 64) {
        unsigned short h0, h1, h2, h3, l0, l1, l2, l3;
        split2(av0.x, h0, l0); split2(av0.y, h1, l1);
        split2(av0.z, h2, l2); split2(av0.w, h3, l3);
        uint2 ahp = make_uint2((unsigned)h0 | ((unsigned)h1 << 16),
                               (unsigned)h2 | ((unsigned)h3 << 16));
        uint2 alp = make_uint2((unsigned)l0 | ((unsigned)l1 << 16),
                               (unsigned)l2 | ((unsigned)l3 << 16));
        uint2 bhw = bh0, blw = bl0;
        __syncthreads();
        *(uint2*)(Ah + asb) = ahp;
        *(uint2*)(Al + asb) = alp;
        *(uint2*)(Bh + bsb) = bhw;
        *(uint2*)(Bl + bsb) = blw;
        av0 = av1; bh0 = bh1; bl0 = bl1;
        if (k0 + 128 < K) {
            av1 = *(const float4*)(Ap + k0 + 128);
            bh1 = *(const uint2*)(Bhp + k0 + 128);
            bl1 = *(const uint2*)(Blp + k0 + 128);
        }
        __syncthreads();
#pragma unroll
        for (int ks = 0; ks < 2; ++ks) {
            const int kb = ks * 64 + kb0;
            short8 bh = *(const short8*)(Bh + ((bb0 + kb) ^ bxor));
            short8 bl = *(const short8*)(Bl + ((bb0 + kb) ^ bxor));
            short8 ah = *(const short8*)(Ah + ((ab0 + kb) ^ axor));
            short8 al = *(const short8*)(Al + ((ab0 + kb) ^ axor));
            acc = __builtin_amdgcn_mfma_f32_16x16x32_bf16(ah, bh, acc, 0, 0, 0);
            acc = __builtin_amdgcn_mfma_f32_16x16x32_bf16(al, bh, acc, 0, 0, 0);
            acc = __builtin_amdgcn_mfma_f32_16x16x32_bf16(ah, bl, acc, 0, 0, 0);
        }
    }
}

// ---------------------------------------------------------------------------
// 32x64 tile, K=2048, 16 waves = 8 C-fragments x 2 K-halves, 2-deep prefetch.
// ---------------------------------------------------------------------------
__device__ __forceinline__ void tile32_gemm_ks(
    const float* __restrict__ A, int row0,
    const unsigned short* __restrict__ BThi, const unsigned short* __restrict__ BTlo,
    int col0, char* lds, f32x4& acc, int& s_out, int& p_out)
{
    char* Ah = lds;
    char* Al = lds + 8192;
    char* Bh = lds + 16384;
    char* Bl = lds + 32768;
    const int t = threadIdx.x, lane = t & 63, w = t >> 6;
    const int s = w & 7, p = w >> 3;
    s_out = s; p_out = p;
    const int mrow = s >> 2, wcol = s & 3;
    f32x4 z = {0.f, 0.f, 0.f, 0.f};
    acc = z;

    const int ar = t >> 5, ac = (t & 31) << 2;
    const int br = t >> 4, bc = (t & 15) << 3;
    const float* Ap = A + (size_t)(row0 + ar) * HDm + ac;
    const unsigned short* Bhp = BThi + (size_t)(col0 + br) * HDm + bc;
    const unsigned short* Blp = BTlo + (size_t)(col0 + br) * HDm + bc;
    const int asb = (ar * 256 + ac * 2) ^ ((ar & 15) << 4);
    const int bsb = (br * 256 + bc * 2) ^ ((br & 15) << 4);
    const int colr = wcol * 16 + (lane & 15);
    const int arow = mrow * 16 + (lane & 15);
    const int bb0 = colr * 256, ab0 = arow * 256;
    const int bxor = (colr & 15) << 4, axor = (arow & 15) << 4;
    const int kc = p * 128;
    const int kb0 = (lane >> 4) << 4;

    float4 av0 = *(const float4*)(Ap);
    uint4  bh0 = *(const uint4*)(Bhp);
    uint4  bl0 = *(const uint4*)(Blp);
    float4 av1 = *(const float4*)(Ap + 128);
    uint4  bh1 = *(const uint4*)(Bhp + 128);
    uint4  bl1 = *(const uint4*)(Blp + 128);

    for (int k0 = 0; k0 < HDm; k0 += 128) {
        unsigned short h0, h1, h2, h3, l0, l1, l2, l3;
        split2(av0.x, h0, l0); split2(av0.y, h1, l1);
        split2(av0.z, h2, l2); split2(av0.w, h3, l3);
        uint2 ahp = make_uint2((unsigned)h0 | ((unsigned)h1 << 16),
                               (unsigned)h2 | ((unsigned)h3 << 16));
        uint2 alp = make_uint2((unsigned)l0 | ((unsigned)l1 << 16),
                               (unsigned)l2 | ((unsigned)l3 << 16));
        uint4 bhw = bh0, blw = bl0;
        __syncthreads();
        *(uint2*)(Ah + asb) = ahp;
        *(uint2*)(Al + asb) = alp;
        *(uint4*)(Bh + bsb) = bhw;
        *(uint4*)(Bl + bsb) = blw;
        av0 = av1; bh0 = bh1; bl0 = bl1;
        if (k0 + 256 < HDm) {
            av1 = *(const float4*)(Ap + k0 + 256);
            bh1 = *(const uint4*)(Bhp + k0 + 256);
            bl1 = *(const uint4*)(Blp + k0 + 256);
        }
        __syncthreads();
#pragma unroll
        for (int ks = 0; ks < 2; ++ks) {
            const int kb = kc + ks * 64 + kb0;
            short8 bh = *(const short8*)(Bh + ((bb0 + kb) ^ bxor));
            short8 bl = *(const short8*)(Bl + ((bb0 + kb) ^ bxor));
            short8 ah = *(const short8*)(Ah + ((ab0 + kb) ^ axor));
            short8 al = *(const short8*)(Al + ((ab0 + kb) ^ axor));
            acc = __builtin_amdgcn_mfma_f32_16x16x32_bf16(ah, bh, acc, 0, 0, 0);
            acc = __builtin_amdgcn_mfma_f32_16x16x32_bf16(al, bh, acc, 0, 0, 0);
            acc = __builtin_amdgcn_mfma_f32_16x16x32_bf16(ah, bl, acc, 0, 0, 0);
        }
    }
}

// ---------------------------------------------------------------------------
// Prep kernels
// ---------------------------------------------------------------------------
__global__ void k_init(int* active, float* scal, int* nrem)
{
    int i = blockIdx.x * blockDim.x + threadIdx.x;
    if (i < BN) active[i] = 1;
    if (i < 8) scal[i] = 0.f;
    if (i == 0) *nrem = BN;
}

__global__ __launch_bounds__(1024) void k_colsum_wh(const float* __restrict__ RH,
                                                    const float* __restrict__ MH,
                                                    float* scal)
{
    const int col = blockIdx.x * 64 + (threadIdx.x & 63);
    const int rs  = threadIdx.x >> 6;
    float s = 0.f;
    for (int i = rs; i < HDm; i += 16)
        s += fabsf(RH[(size_t)i * HDm + col] * MH[(size_t)i * HDm + col]);
    __shared__ float red[16][64];
    red[rs][threadIdx.x & 63] = s;
    __syncthreads();
    if (threadIdx.x < 64) {
        float c = 0.f;
#pragma unroll
        for (int j = 0; j < 16; ++j) c += red[j][threadIdx.x];
#pragma unroll
        for (int off = 1; off < 64; off <<= 1) c = fmaxf(c, __shfl_xor(c, off));
        if (threadIdx.x == 0)
            atomicMax((unsigned int*)&scal[0], __float_as_uint(c));
    }
}

__global__ __launch_bounds__(1024) void k_colsum_whl(const float* __restrict__ RHL,
                                                     const float* __restrict__ MHL,
                                                     float* scal)
{
    const int col = blockIdx.x * 64 + (threadIdx.x & 63);
    const int rs  = threadIdx.x >> 6;
    float s = 0.f;
    if (col < LD) {
        for (int i = rs; i < HDm; i += 16)
            s += fabsf(RHL[(size_t)i * LD + col] * MHL[(size_t)i * LD + col]);
    }
    __shared__ float red[16][64];
    red[rs][threadIdx.x & 63] = s;
    __syncthreads();
    if (threadIdx.x < 64) {
        float c = 0.f;
#pragma unroll
        for (int j = 0; j < 16; ++j) c += red[j][threadIdx.x];
#pragma unroll
        for (int off = 1; off < 64; off <<= 1) c = fmaxf(c, __shfl_xor(c, off));
        if (threadIdx.x == 0)
            atomicMax((unsigned int*)&scal[1], __float_as_uint(c));
    }
}

__global__ void k_scalars(float* scal)
{
    if (threadIdx.x == 0 && blockIdx.x == 0) {
        scal[2] = 0.95f / fmaxf(scal[0], 1e-8f);
        scal[3] = scal[1] * 19.f;
    }
}

__global__ __launch_bounds__(256) void k_wsplit(
    const float* __restrict__ R, const float* __restrict__ M,
    unsigned short* __restrict__ Ohi, unsigned short* __restrict__ Olo,
    int NR, int NC, int NCp, const float* __restrict__ scal, int scidx)
{
    __shared__ float T[64][65];
    const int nct = NCp >> 6;
    const int c0 = (blockIdx.x % nct) << 6;
    const int r0 = (blockIdx.x / nct) << 6;
    const float s = (scidx >= 0) ? scal[scidx] : 1.f;
    const int t = threadIdx.x;
    const int ir = t >> 2, ics = (t & 3) << 4;
#pragma unroll
    for (int i = 0; i < 16; ++i) {
        const int c = c0 + ics + i;
        float v = 0.f;
        if (c < NC) {
            const size_t idx = (size_t)(r0 + ir) * NC + c;
            v = R[idx] * M[idx] * s;
        }
        T[ir][ics + i] = v;
    }
    __syncthreads();
    const int oc = t >> 2, ors = (t & 3) << 4;
    unsigned short hb[16], lb[16];
#pragma unroll
    for (int i = 0; i < 16; ++i) split2(T[ors + i][oc], hb[i], lb[i]);
    const size_t base = (size_t)(c0 + oc) * NR + r0 + ors;
    uint4 v;
    v.x = hb[0] | ((unsigned)hb[1] << 16);  v.y = hb[2] | ((unsigned)hb[3] << 16);
    v.z = hb[4] | ((unsigned)hb[5] << 16);  v.w = hb[6] | ((unsigned)hb[7] << 16);
    *(uint4*)(Ohi + base) = v;
    v.x = hb[8] | ((unsigned)hb[9] << 16);  v.y = hb[10] | ((unsigned)hb[11] << 16);
    v.z = hb[12] | ((unsigned)hb[13] << 16); v.w = hb[14] | ((unsigned)hb[15] << 16);
    *(uint4*)(Ohi + base + 8) = v;
    v.x = lb[0] | ((unsigned)lb[1] << 16);  v.y = lb[2] | ((unsigned)lb[3] << 16);
    v.z = lb[4] | ((unsigned)lb[5] << 16);  v.w = lb[6] | ((unsigned)lb[7] << 16);
    *(uint4*)(Olo + base) = v;
    v.x = lb[8] | ((unsigned)lb[9] << 16);  v.y = lb[10] | ((unsigned)lb[11] << 16);
    v.z = lb[12] | ((unsigned)lb[13] << 16); v.w = lb[14] | ((unsigned)lb[15] << 16);
    *(uint4*)(Olo + base + 8) = v;
}

__global__ __launch_bounds__(1024) void k_drive_mfma(
    const float* __restrict__ x,
    const unsigned short* __restrict__ WIHThi, const unsigned short* __restrict__ WIHTlo,
    const float* __restrict__ BH, float* __restrict__ drive)
{
    __shared__ char lds[32768];
    f32x4 acc;
    const int row0 = (blockIdx.x >> 5) * 64, col0 = (blockIdx.x & 31) * 64;
    tile64_gemm(x, ID, row0, WIHThi, WIHTlo, ID, col0, ID, lds, acc);
    const int lane = threadIdx.x & 63, w = threadIdx.x >> 6;
    const int gc = col0 + (w & 3) * 16 + (lane & 15);
    const int gr0 = row0 + (w >> 2) * 16 + ((lane >> 4) << 2);
    const float bh = BH[gc];
#pragma unroll
    for (int r = 0; r < 4; ++r)
        drive[(size_t)(gr0 + r) * HDm + gc] = acc[r] + bh;
}

// ---------------------------------------------------------------------------
// Step kernels. All cross-block communication is dispatch-separated:
//   k_p1 : reads active;  writes Hn, dhp           (pure w.r.t. state)
//   k_p2 : reads active;  writes logits, m1p, m2p  (pure w.r.t. state)
//   k_cert: reads dhp/m1p/m2p/logits; writes active, nrem, out (sole writer)
// ---------------------------------------------------------------------------
__global__ __launch_bounds__(1024) void k_p1(
    const unsigned short* __restrict__ WHThi, const unsigned short* __restrict__ WHTlo,
    const float* __restrict__ drive, float* __restrict__ Ha, float* __restrict__ Hb,
    const int* __restrict__ active, const int* __restrict__ nrem,
    float* __restrict__ dhp, int t)
{
    __shared__ char lds[32768];
    __shared__ int s_any;
    if (*nrem == 0) return;
    const int bid = blockIdx.x, tid = threadIdx.x;
    const int row0m = (bid >> 5) << 6;
    const float* Hs = (t & 1) ? Ha : Hb;
    float* Hn = (t & 1) ? Hb : Ha;

    const int col0 = (bid & 31) * 64;
    if (tid < 64) {
        int a = active[row0m + tid];
        unsigned long long bl = __ballot(a != 0);
        if (tid == 0) s_any = (bl != 0ull);
    }
    __syncthreads();
    if (!s_any) return;

    f32x4 acc;
    tile64_gemm(Hs, HDm, row0m, WHThi, WHTlo, HDm, col0, HDm, lds, acc);
    const int lane = tid & 63, w = tid >> 6;
    const int gc = col0 + (w & 3) * 16 + (lane & 15);
    const int gr0 = row0m + (w >> 2) * 16 + ((lane >> 4) << 2);
    float dh4[4];
#pragma unroll
    for (int r = 0; r < 4; ++r) {
        const int gr = gr0 + r;
        const float old = Hs[(size_t)gr * HDm + gc];
        const float pre = acc[r] + drive[(size_t)gr * HDm + gc];
        const float av = pre >= 0.f ? pre : ALPHAc * pre;
        const int act = active[gr];
        const float nv = act ? av : old;
        Hn[(size_t)gr * HDm + gc] = nv;
        dh4[r] = fabsf(nv - old);
    }
#pragma unroll
    for (int off = 1; off < 16; off <<= 1)
#pragma unroll
        for (int r = 0; r < 4; ++r)
            dh4[r] = fmaxf(dh4[r], __shfl_xor(dh4[r], off));
    __syncthreads();
    float (*sdh)[4] = (float(*)[4])lds;
    if ((lane & 15) == 0) {
        const int rl0 = (w >> 2) * 16 + ((lane >> 4) << 2);
#pragma unroll
        for (int r = 0; r < 4; ++r) sdh[rl0 + r][w & 3] = dh4[r];
    }
    __syncthreads();
    if (tid < 64) {
        float d = fmaxf(fmaxf(sdh[tid][0], sdh[tid][1]),
                        fmaxf(sdh[tid][2], sdh[tid][3]));
        dhp[(size_t)(row0m + tid) * 32 + (bid & 31)] = d;
    }
}

__global__ __launch_bounds__(1024) void k_p2(
    const unsigned short* __restrict__ WHLThi, const unsigned short* __restrict__ WHLTlo,
    const float* __restrict__ BL, const float* __restrict__ Ha, const float* __restrict__ Hb,
    float* __restrict__ logits, const int* __restrict__ active, const int* __restrict__ nrem,
    float* __restrict__ m1p, float* __restrict__ m2p, int t)
{
    __shared__ char lds[49152];
    __shared__ int s_any;
    if (*nrem == 0) return;
    const int bid = blockIdx.x, tid = threadIdx.x;
    const float* Hn = (t & 1) ? Hb : Ha;
    const int row0 = (bid >> 4) * 32, col0 = (bid & 15) * 64;

    if (tid < 64) {
        int a = (tid < 32) ? active[row0 + tid] : 0;
        unsigned long long bl = __ballot(a != 0);
        if (tid == 0) s_any = (bl != 0ull);
    }
    __syncthreads();
    if (!s_any) return;

    f32x4 acc;
    int s, p;
    tile32_gemm_ks(Hn, row0, WHLThi, WHLTlo, col0, lds, acc, s, p);
    const int lane = tid & 63;
    f32x4* red = (f32x4*)lds;
    float (*st1)[4] = (float(*)[4])(lds + 36864);
    float (*st2)[4] = (float(*)[4])(lds + 37888);
    __syncthreads();
    if (p == 1) red[s * 64 + lane] = acc;
    __syncthreads();
    if (p == 0) {
        f32x4 o = red[s * 64 + lane];
        const int gc = col0 + (s & 3) * 16 + (lane & 15);
        const int gr0 = row0 + (s >> 2) * 16 + ((lane >> 4) << 2);
        const bool okc = gc < LD;
        const float blv = okc ? BL[gc] : 0.f;
        float m1a[4], m2a[4];
#pragma unroll
        for (int r = 0; r < 4; ++r) {
            const float v = acc[r] + o[r] + blv;
            if (okc) logits[(size_t)(gr0 + r) * LD + gc] = v;
            m1a[r] = okc ? v : -3.4e38f;
            m2a[r] = -3.4e38f;
        }
#pragma unroll
        for (int off = 1; off < 16; off <<= 1) {
#pragma unroll
            for (int r = 0; r < 4; ++r) {
                float o1 = __shfl_xor(m1a[r], off);
                float o2 = __shfl_xor(m2a[r], off);
                if (o1 > m1a[r]) { m2a[r] = fmaxf(m1a[r], o2); m1a[r] = o1; }
                else m2a[r] = fmaxf(m2a[r], o1);
            }
        }
        if ((lane & 15) == 0) {
            const int rl0 = (s >> 2) * 16 + ((lane >> 4) << 2);
#pragma unroll
            for (int r = 0; r < 4; ++r) {
                st1[rl0 + r][s & 3] = m1a[r];
                st2[rl0 + r][s & 3] = m2a[r];
            }
        }
    }
    __syncthreads();
    if (tid < 32) {
        float M1 = st1[tid][0], M2 = st2[tid][0];
#pragma unroll
        for (int g = 1; g < 4; ++g) {
            float o1 = st1[tid][g], o2 = st2[tid][g];
            if (o1 > M1) { M2 = fmaxf(M1, o2); M1 = o1; }
            else M2 = fmaxf(M2, o1);
        }
        m1p[(size_t)(row0 + tid) * 16 + (bid & 15)] = M1;
        m2p[(size_t)(row0 + tid) * 16 + (bid & 15)] = M2;
    }
}

// Certification: 8 blocks x 1024 threads; block owns rows [bid*64, bid*64+64).
// Sole writer of active/nrem/out. Reads this step's partials and logits.
__global__ __launch_bounds__(1024) void k_cert(
    const float* __restrict__ logits, float* __restrict__ out,
    int* __restrict__ active, int* __restrict__ nrem,
    const float* __restrict__ scal,
    const float* __restrict__ dhp, const float* __restrict__ m1p,
    const float* __restrict__ m2p)
{
    __shared__ int snew[64];
    if (*nrem == 0) return;
    const int bid = blockIdx.x, tid = threadIdx.x;
    const int row0 = bid * 64;
    const float gamma2 = 2.f * scal[3];
    const int rl = tid >> 4, j = tid & 15;       // 64 rows x 16 lanes
    const int r = row0 + rl;
    const int act = active[r];
    float dh = fmaxf(dhp[(size_t)r * 32 + j], dhp[(size_t)r * 32 + 16 + j]);
    float M1 = m1p[(size_t)r * 16 + j], M2 = m2p[(size_t)r * 16 + j];
#pragma unroll
    for (int off = 1; off < 16; off <<= 1) {     // xor-butterfly stays in 16-lane group
        dh = fmaxf(dh, __shfl_xor(dh, off));
        float o1 = __shfl_xor(M1, off), o2 = __shfl_xor(M2, off);
        if (o1 > M1) { M2 = fmaxf(M1, o2); M1 = o1; }
        else M2 = fmaxf(M2, o1);
    }
    if (j == 0) {
        int nw = act && ((M1 - M2) > gamma2 * dh);
        snew[rl] = nw;
        if (nw) active[r] = 0;
    }
    __syncthreads();
    int cnt = 0;
    for (int rl2 = 0; rl2 < 64; ++rl2) {
        if (snew[rl2]) {
            ++cnt;
            const float* lr = logits + (size_t)(row0 + rl2) * LD;
            float* orow = out + (size_t)(row0 + rl2) * LD;
            for (int jj = tid; jj < LD; jj += 1024) orow[jj] = lr[jj];
        }
    }
    if (tid == 0 && cnt) atomicAdd(nrem, -cnt);
}

// rows still active after the loop take the last-step logits
__global__ __launch_bounds__(1024) void k_tail(
    const float* __restrict__ logits, const int* __restrict__ active,
    float* __restrict__ out)
{
    const int row0 = blockIdx.x * 64;
    for (int rl = 0; rl < 64; ++rl) {
        if (active[row0 + rl]) {
            const float* lr = logits + (size_t)(row0 + rl) * LD;
            float* orow = out + (size_t)(row0 + rl) * LD;
            for (int jj = threadIdx.x; jj < LD; jj += 1024) orow[jj] = lr[jj];
        }
    }
}

// ---------------------------------------------------------------------------
extern "C" void kernel_launch(void* const* d_in, const int* in_sizes, int n_in,
                              void* d_out, int out_size, void* d_ws, size_t ws_size,
                              hipStream_t stream)
{
    const float* x   = (const float*)d_in[0];
    const float* RIH = (const float*)d_in[1];
    const float* RH  = (const float*)d_in[2];
    const float* RHL = (const float*)d_in[3];
    const float* BH  = (const float*)d_in[4];
    const float* BL  = (const float*)d_in[5];
    const float* MIH = (const float*)d_in[6];
    const float* MH  = (const float*)d_in[7];
    const float* MHL = (const float*)d_in[8];
    float* out = (float*)d_out;
    char* w = (char*)d_ws;

    unsigned short* WHThi = (unsigned short*)(w);                 //  8 MB
    unsigned short* WHTlo = (unsigned short*)(w + 8388608);       //  8 MB
    unsigned short* WXhi  = (unsigned short*)(w + 16777216);      //  4 MB
    unsigned short* WXlo  = (unsigned short*)(w + 20971520);      //  4 MB
    float* drive  = (float*)(w + 25165824);                       //  4 MB
    float* Ha     = (float*)(w + 29360128);                       //  4 MB
    float* Hb     = (float*)(w + 33554432);                       //  4 MB
    float* logits = (float*)(w + 37748736);                       //  2 MB
    float* scal   = (float*)(w + 39796736);                       //  8 f
    int*   active = (int*)(w + 39796800);                         //  512 i
    int*   nrem   = (int*)(w + 39798848);                         //  1 i
    float* dhp    = (float*)(w + 39799296);                       //  64 KB
    float* m1p    = (float*)(w + 39864832);                       //  32 KB
    float* m2p    = (float*)(w + 39897600);                       //  32 KB

    k_init<<<2, 256, 0, stream>>>(active, scal, nrem);
    k_colsum_wh<<<32, 1024, 0, stream>>>(RH, MH, scal);
    k_colsum_whl<<<16, 1024, 0, stream>>>(RHL, MHL, scal);
    k_scalars<<<1, 64, 0, stream>>>(scal);
    k_wsplit<<<512, 256, 0, stream>>>(RIH, MIH, WXhi, WXlo, ID, HDm, HDm, scal, -1);
    k_drive_mfma<<<256, 1024, 0, stream>>>(x, WXhi, WXlo, BH, drive);
    k_wsplit<<<1024, 256, 0, stream>>>(RH, MH, WHThi, WHTlo, HDm, HDm, HDm, scal, 2);
    k_wsplit<<<512, 256, 0, stream>>>(RHL, MHL, WXhi, WXlo, HDm, LD, 1024, scal, -1);
    hipMemsetAsync(Ha, 0, (size_t)BN * HDm * sizeof(float), stream);

    for (int t = 1; t <= TMAXc; ++t) {
        k_p1<<<256, 1024, 0, stream>>>(WHThi, WHTlo, drive, Ha, Hb,
                                       active, nrem, dhp, t);
        k_p2<<<256, 1024, 0, stream>>>(WXhi, WXlo, BL, Ha, Hb, logits,
                                       active, nrem, m1p, m2p, t);
        k_cert<<<8, 1024, 0, stream>>>(logits, out, active, nrem, scal,
                                       dhp, m1p, m2p);
    }
    k_tail<<<8, 1024, 0, stream>>>(logits, active, out);
}

// Round 10
// 1729.829 us; speedup vs baseline: 7.8556x; 1.1367x over previous
//
#include <hip/hip_runtime.h>

typedef __attribute__((ext_vector_type(8))) short short8;
typedef __attribute__((ext_vector_type(4))) float f32x4;

static constexpr int BN    = 512;
static constexpr int ID    = 1024;
static constexpr int HDm   = 2048;
static constexpr int LD    = 1000;
static constexpr int TMAXc = 32;
static constexpr float ALPHAc = 0.05f;

// ---------------- bf16 split helpers (x ~= hi + lo, each bf16) ----------------
__device__ __forceinline__ unsigned short f2bf(float x) {
    unsigned u = __float_as_uint(x);
    u += 0x7fffu + ((u >> 16) & 1u);           // RNE
    return (unsigned short)(u >> 16);
}
__device__ __forceinline__ float bf2f(unsigned short h) {
    return __uint_as_float(((unsigned)h) << 16);
}
__device__ __forceinline__ void split2(float x, unsigned short& hi, unsigned short& lo) {
    hi = f2bf(x);
    lo = f2bf(x - bf2f(hi));
}

// ---------------------------------------------------------------------------
// 64x64 tile, 1024 threads (16 waves, one 16x16 C-fragment each), K-step 64,
// 2-deep register prefetch, split-bf16 3-term MFMA (~fp32 accuracy).
// SPLITA=true: A is fp32, split during staging. false: A pre-split bf16 hi/lo.
// LDS XOR swizzle: byte ^= (row&7)<<4.
// ---------------------------------------------------------------------------
template<bool SPLITA>
__device__ __forceinline__ void tile64_gemm(
    const float* __restrict__ Af,
    const unsigned short* __restrict__ Ahi, const unsigned short* __restrict__ Alo,
    int lda, int row0,
    const unsigned short* __restrict__ BThi, const unsigned short* __restrict__ BTlo,
    int ldk, int col0, int K, char* lds, f32x4& acc)
{
    char* Ah = lds;
    char* Al = lds + 8192;
    char* Bh = lds + 16384;
    char* Bl = lds + 24576;
    const int t = threadIdx.x, lane = t & 63, w = t >> 6;
    f32x4 z = {0.f, 0.f, 0.f, 0.f};
    acc = z;

    const int ar = t >> 4, ac = (t & 15) << 2;
    const int br = t >> 4, bc = (t & 15) << 2;
    const unsigned short* Bhp = BThi + (size_t)(col0 + br) * ldk + bc;
    const unsigned short* Blp = BTlo + (size_t)(col0 + br) * ldk + bc;
    const int asb = (ar * 128 + ac * 2) ^ ((ar & 7) << 4);
    const int bsb = (br * 128 + bc * 2) ^ ((br & 7) << 4);
    const int colr = (w & 3) * 16 + (lane & 15);
    const int arow = (w >> 2) * 16 + (lane & 15);
    const int bb0 = colr * 128, ab0 = arow * 128;
    const int bxor = (colr & 7) << 4, axor = (arow & 7) << 4;
    const int kb0 = (lane >> 4) << 4;

    const float* Ap = SPLITA ? (Af + (size_t)(row0 + ar) * lda + ac) : nullptr;
    const unsigned short* Ahp = SPLITA ? nullptr : (Ahi + (size_t)(row0 + ar) * lda + ac);
    const unsigned short* Alp = SPLITA ? nullptr : (Alo + (size_t)(row0 + ar) * lda + ac);

    float4 av0, av1;
    uint2 ah0, al0, ah1, al1;
    uint2 bh0 = *(const uint2*)Bhp,        bl0 = *(const uint2*)Blp;
    uint2 bh1 = *(const uint2*)(Bhp + 64), bl1 = *(const uint2*)(Blp + 64);
    if constexpr (SPLITA) {
        av0 = *(const float4*)Ap;
        av1 = *(const float4*)(Ap + 64);
    } else {
        ah0 = *(const uint2*)Ahp;        al0 = *(const uint2*)Alp;
        ah1 = *(const uint2*)(Ahp + 64); al1 = *(const uint2*)(Alp + 64);
    }

    for (int k0 = 0; k0 < K; k0 += 64) {
        uint2 aw_h, aw_l;
        if constexpr (SPLITA) {
            unsigned short h0, h1, h2, h3, l0, l1, l2, l3;
            split2(av0.x, h0, l0); split2(av0.y, h1, l1);
            split2(av0.z, h2, l2); split2(av0.w, h3, l3);
            aw_h = make_uint2((unsigned)h0 | ((unsigned)h1 << 16),
                              (unsigned)h2 | ((unsigned)h3 << 16));
            aw_l = make_uint2((unsigned)l0 | ((unsigned)l1 << 16),
                              (unsigned)l2 | ((unsigned)l3 << 16));
        } else { aw_h = ah0; aw_l = al0; }
        uint2 bw_h = bh0, bw_l = bl0;
        __syncthreads();                       // prior LDS readers done
        *(uint2*)(Ah + asb) = aw_h;
        *(uint2*)(Al + asb) = aw_l;
        *(uint2*)(Bh + bsb) = bw_h;
        *(uint2*)(Bl + bsb) = bw_l;
        if constexpr (SPLITA) { av0 = av1; } else { ah0 = ah1; al0 = al1; }
        bh0 = bh1; bl0 = bl1;
        if (k0 + 128 < K) {
            if constexpr (SPLITA) {
                av1 = *(const float4*)(Ap + k0 + 128);
            } else {
                ah1 = *(const uint2*)(Ahp + k0 + 128);
                al1 = *(const uint2*)(Alp + k0 + 128);
            }
            bh1 = *(const uint2*)(Bhp + k0 + 128);
            bl1 = *(const uint2*)(Blp + k0 + 128);
        }
        __syncthreads();
#pragma unroll
        for (int ks = 0; ks < 2; ++ks) {
            const int kb = ks * 64 + kb0;
            short8 bh = *(const short8*)(Bh + ((bb0 + kb) ^ bxor));
            short8 bl = *(const short8*)(Bl + ((bb0 + kb) ^ bxor));
            short8 ah = *(const short8*)(Ah + ((ab0 + kb) ^ axor));
            short8 al = *(const short8*)(Al + ((ab0 + kb) ^ axor));
            acc = __builtin_amdgcn_mfma_f32_16x16x32_bf16(ah, bh, acc, 0, 0, 0);
            acc = __builtin_amdgcn_mfma_f32_16x16x32_bf16(al, bh, acc, 0, 0, 0);
            acc = __builtin_amdgcn_mfma_f32_16x16x32_bf16(ah, bl, acc, 0, 0, 0);
        }
    }
}

// ---------------------------------------------------------------------------
// 32x64 tile, K=2048, 16 waves = 8 C-fragments x 2 K-halves, 2-deep prefetch.
// A pre-split bf16 hi/lo. LDS swizzle: ^ (row&15)<<4.
// ---------------------------------------------------------------------------
__device__ __forceinline__ void tile32_gemm_ks(
    const unsigned short* __restrict__ Ahi, const unsigned short* __restrict__ Alo, int row0,
    const unsigned short* __restrict__ BThi, const unsigned short* __restrict__ BTlo,
    int col0, char* lds, f32x4& acc, int& s_out, int& p_out)
{
    char* Ah = lds;
    char* Al = lds + 8192;
    char* Bh = lds + 16384;
    char* Bl = lds + 32768;
    const int t = threadIdx.x, lane = t & 63, w = t >> 6;
    const int s = w & 7, p = w >> 3;
    s_out = s; p_out = p;
    f32x4 z = {0.f, 0.f, 0.f, 0.f};
    acc = z;

    const int ar = t >> 5, ac = (t & 31) << 2;
    const int br = t >> 4, bc = (t & 15) << 3;
    const unsigned short* Ahp = Ahi + (size_t)(row0 + ar) * HDm + ac;
    const unsigned short* Alp = Alo + (size_t)(row0 + ar) * HDm + ac;
    const unsigned short* Bhp = BThi + (size_t)(col0 + br) * HDm + bc;
    const unsigned short* Blp = BTlo + (size_t)(col0 + br) * HDm + bc;
    const int asb = (ar * 256 + ac * 2) ^ ((ar & 15) << 4);
    const int bsb = (br * 256 + bc * 2) ^ ((br & 15) << 4);
    const int colr = (s & 3) * 16 + (lane & 15);
    const int arow = (s >> 2) * 16 + (lane & 15);
    const int bb0 = colr * 256, ab0 = arow * 256;
    const int bxor = (colr & 15) << 4, axor = (arow & 15) << 4;
    const int kc = p * 128;
    const int kb0 = (lane >> 4) << 4;

    uint2 ah0 = *(const uint2*)Ahp,         al0 = *(const uint2*)Alp;
    uint4 bh0 = *(const uint4*)Bhp,         bl0 = *(const uint4*)Blp;
    uint2 ah1 = *(const uint2*)(Ahp + 128), al1 = *(const uint2*)(Alp + 128);
    uint4 bh1 = *(const uint4*)(Bhp + 128), bl1 = *(const uint4*)(Blp + 128);

    for (int k0 = 0; k0 < HDm; k0 += 128) {
        uint2 aw_h = ah0, aw_l = al0;
        uint4 bw_h = bh0, bw_l = bl0;
        __syncthreads();
        *(uint2*)(Ah + asb) = aw_h;
        *(uint2*)(Al + asb) = aw_l;
        *(uint4*)(Bh + bsb) = bw_h;
        *(uint4*)(Bl + bsb) = bw_l;
        ah0 = ah1; al0 = al1; bh0 = bh1; bl0 = bl1;
        if (k0 + 256 < HDm) {
            ah1 = *(const uint2*)(Ahp + k0 + 256);
            al1 = *(const uint2*)(Alp + k0 + 256);
            bh1 = *(const uint4*)(Bhp + k0 + 256);
            bl1 = *(const uint4*)(Blp + k0 + 256);
        }
        __syncthreads();
#pragma unroll
        for (int ks = 0; ks < 2; ++ks) {
            const int kb = kc + ks * 64 + kb0;
            short8 bh = *(const short8*)(Bh + ((bb0 + kb) ^ bxor));
            short8 bl = *(const short8*)(Bl + ((bb0 + kb) ^ bxor));
            short8 ah = *(const short8*)(Ah + ((ab0 + kb) ^ axor));
            short8 al = *(const short8*)(Al + ((ab0 + kb) ^ axor));
            acc = __builtin_amdgcn_mfma_f32_16x16x32_bf16(ah, bh, acc, 0, 0, 0);
            acc = __builtin_amdgcn_mfma_f32_16x16x32_bf16(al, bh, acc, 0, 0, 0);
            acc = __builtin_amdgcn_mfma_f32_16x16x32_bf16(ah, bl, acc, 0, 0, 0);
        }
    }
}

// ---------------------------------------------------------------------------
// Prep kernels
// ---------------------------------------------------------------------------
__global__ void k_init(int* active, int* cnt, float* scal)
{
    int i = blockIdx.x * blockDim.x + threadIdx.x;
    if (i < 2 * BN) active[i] = 1;
    if (i < 16) cnt[i] = 64;
    if (i < 8) scal[i] = 0.f;
}

// partial column-L1 of RH*MH: 256 blocks = 32 colTiles x 8 rowSlices
__global__ __launch_bounds__(256) void k_colsum_wh(const float* __restrict__ RH,
                                                   const float* __restrict__ MH,
                                                   float* __restrict__ part)
{
    const int colTile = blockIdx.x >> 3, rs = blockIdx.x & 7;
    const int col = colTile * 64 + (threadIdx.x & 63);
    const int rq = threadIdx.x >> 6;
    const int r0 = rs * 256;
    float s = 0.f;
    for (int i = r0 + rq; i < r0 + 256; i += 4)
        s += fabsf(RH[(size_t)i * HDm + col] * MH[(size_t)i * HDm + col]);
    __shared__ float red[4][64];
    red[rq][threadIdx.x & 63] = s;
    __syncthreads();
    if (threadIdx.x < 64)
        part[(size_t)rs * HDm + col] = red[0][threadIdx.x] + red[1][threadIdx.x] +
                                       red[2][threadIdx.x] + red[3][threadIdx.x];
}

// partial column-L1 of RHL*MHL: 128 blocks = 16 colTiles x 8 rowSlices
__global__ __launch_bounds__(256) void k_colsum_whl(const float* __restrict__ RHL,
                                                    const float* __restrict__ MHL,
                                                    float* __restrict__ part)
{
    const int colTile = blockIdx.x >> 3, rs = blockIdx.x & 7;
    const int col = colTile * 64 + (threadIdx.x & 63);
    const int rq = threadIdx.x >> 6;
    const int r0 = rs * 256;
    float s = 0.f;
    if (col < LD) {
        for (int i = r0 + rq; i < r0 + 256; i += 4)
            s += fabsf(RHL[(size_t)i * LD + col] * MHL[(size_t)i * LD + col]);
    }
    __shared__ float red[4][64];
    red[rq][threadIdx.x & 63] = s;
    __syncthreads();
    if (threadIdx.x < 64)
        part[(size_t)rs * 1024 + col] = red[0][threadIdx.x] + red[1][threadIdx.x] +
                                        red[2][threadIdx.x] + red[3][threadIdx.x];
}

// final reduce of both partials -> scal[2] (W_H scale), scal[3] (gamma_coef)
__global__ __launch_bounds__(1024) void k_scalars(const float* __restrict__ part_wh,
                                                  const float* __restrict__ part_whl,
                                                  float* scal)
{
    float m1 = 0.f, m2 = 0.f;
    for (int c = threadIdx.x; c < HDm; c += 1024) {
        float s = 0.f;
#pragma unroll
        for (int k = 0; k < 8; ++k) s += part_wh[(size_t)k * HDm + c];
        m1 = fmaxf(m1, s);
    }
    {
        const int c = threadIdx.x;
        if (c < 1024) {
            float s = 0.f;
#pragma unroll
            for (int k = 0; k < 8; ++k) s += part_whl[(size_t)k * 1024 + c];
            m2 = fmaxf(m2, s);
        }
    }
#pragma unroll
    for (int off = 1; off < 64; off <<= 1) {
        m1 = fmaxf(m1, __shfl_xor(m1, off));
        m2 = fmaxf(m2, __shfl_xor(m2, off));
    }
    __shared__ float r1[16], r2[16];
    if ((threadIdx.x & 63) == 0) { r1[threadIdx.x >> 6] = m1; r2[threadIdx.x >> 6] = m2; }
    __syncthreads();
    if (threadIdx.x == 0) {
        float a = 0.f, b = 0.f;
#pragma unroll
        for (int i = 0; i < 16; ++i) { a = fmaxf(a, r1[i]); b = fmaxf(b, r2[i]); }
        scal[2] = 0.95f / fmaxf(a, 1e-8f);
        scal[3] = b * 19.f;
    }
}

// Transposed split:  O{hi,lo}[c][r] = split(R[r][c] * M[r][c] * s)
__global__ __launch_bounds__(256) void k_wsplit(
    const float* __restrict__ R, const float* __restrict__ M,
    unsigned short* __restrict__ Ohi, unsigned short* __restrict__ Olo,
    int NR, int NC, int NCp, const float* __restrict__ scal, int scidx)
{
    __shared__ float T[64][65];
    const int nct = NCp >> 6;
    const int c0 = (blockIdx.x % nct) << 6;
    const int r0 = (blockIdx.x / nct) << 6;
    const float s = (scidx >= 0) ? scal[scidx] : 1.f;
    const int t = threadIdx.x;
    const int ir = t >> 2, ics = (t & 3) << 4;
#pragma unroll
    for (int i = 0; i < 16; ++i) {
        const int c = c0 + ics + i;
        float v = 0.f;
        if (c < NC) {
            const size_t idx = (size_t)(r0 + ir) * NC + c;
            v = R[idx] * M[idx] * s;
        }
        T[ir][ics + i] = v;
    }
    __syncthreads();
    const int oc = t >> 2, ors = (t & 3) << 4;
    unsigned short hb[16], lb[16];
#pragma unroll
    for (int i = 0; i < 16; ++i) split2(T[ors + i][oc], hb[i], lb[i]);
    const size_t base = (size_t)(c0 + oc) * NR + r0 + ors;
    uint4 v;
    v.x = hb[0] | ((unsigned)hb[1] << 16);  v.y = hb[2] | ((unsigned)hb[3] << 16);
    v.z = hb[4] | ((unsigned)hb[5] << 16);  v.w = hb[6] | ((unsigned)hb[7] << 16);
    *(uint4*)(Ohi + base) = v;
    v.x = hb[8] | ((unsigned)hb[9] << 16);  v.y = hb[10] | ((unsigned)hb[11] << 16);
    v.z = hb[12] | ((unsigned)hb[13] << 16); v.w = hb[14] | ((unsigned)hb[15] << 16);
    *(uint4*)(Ohi + base + 8) = v;
    v.x = lb[0] | ((unsigned)lb[1] << 16);  v.y = lb[2] | ((unsigned)lb[3] << 16);
    v.z = lb[4] | ((unsigned)lb[5] << 16);  v.w = lb[6] | ((unsigned)lb[7] << 16);
    *(uint4*)(Olo + base) = v;
    v.x = lb[8] | ((unsigned)lb[9] << 16);  v.y = lb[10] | ((unsigned)lb[11] << 16);
    v.z = lb[12] | ((unsigned)lb[13] << 16); v.w = lb[14] | ((unsigned)lb[15] << 16);
    *(uint4*)(Olo + base + 8) = v;
}

__global__ __launch_bounds__(1024) void k_drive_mfma(
    const float* __restrict__ x,
    const unsigned short* __restrict__ WIHThi, const unsigned short* __restrict__ WIHTlo,
    const float* __restrict__ BH, float* __restrict__ drive)
{
    __shared__ char lds[32768];
    f32x4 acc;
    const int row0 = (blockIdx.x >> 5) * 64, col0 = (blockIdx.x & 31) * 64;
    tile64_gemm<true>(x, nullptr, nullptr, ID, row0, WIHThi, WIHTlo, ID, col0, ID, lds, acc);
    const int lane = threadIdx.x & 63, w = threadIdx.x >> 6;
    const int gc = col0 + (w & 3) * 16 + (lane & 15);
    const int gr0 = row0 + (w >> 2) * 16 + ((lane >> 4) << 2);
    const float bh = BH[gc];
#pragma unroll
    for (int r = 0; r < 4; ++r)
        drive[(size_t)(gr0 + r) * HDm + gc] = acc[r] + bh;
}

// ---------------------------------------------------------------------------
// k_p1(t): finalize(t-1) from parity-(t-1) partials (all arrays it READS are
// frozen during this dispatch; all it WRITES are parity-t or identical-value),
// then Hn = select(active, LeakyReLU(Hs@W_H + drive), Hs) + dH partials.
// ---------------------------------------------------------------------------
__global__ __launch_bounds__(1024) void k_p1(
    const unsigned short* __restrict__ WHThi, const unsigned short* __restrict__ WHTlo,
    const float* __restrict__ drive,
    unsigned short* __restrict__ HAhi, unsigned short* __restrict__ HAlo,
    unsigned short* __restrict__ HBhi, unsigned short* __restrict__ HBlo,
    const float* __restrict__ logits, float* __restrict__ out,
    int* __restrict__ active, int* __restrict__ cnt, const float* __restrict__ scal,
    float* __restrict__ dhp, const float* __restrict__ m1p, const float* __restrict__ m2p,
    int t)
{
    __shared__ char lds[32768];
    __shared__ int sact[64], snew[64];
    __shared__ int s_cnt;
    const int pp = (t - 1) & 1, pc = t & 1;
    {   // frozen early-exit gate (written by p1(t-1) only)
        const int* cp = cnt + pp * 8;
        int sum = 0;
#pragma unroll
        for (int i = 0; i < 8; ++i) sum += cp[i];
        if (sum == 0) return;
    }
    const int bid = blockIdx.x, tid = threadIdx.x;
    const int rt = bid >> 5, row0m = rt << 6, col0 = (bid & 31) * 64;
    const int* actP = active + pp * BN;
    int* actC = active + pc * BN;
    const unsigned short* Hshi = (t & 1) ? HAhi : HBhi;
    const unsigned short* Hslo = (t & 1) ? HAlo : HBlo;
    unsigned short* Hnhi = (t & 1) ? HBhi : HAhi;
    unsigned short* Hnlo = (t & 1) ? HBlo : HAlo;
    const float* dhpP = dhp + (size_t)pp * BN * 32;
    float* dhpC = dhp + (size_t)pc * BN * 32;

    // ---- finalize(t-1): certification from frozen partials ----
    if (t > 1) {
        const float gamma2 = 2.f * scal[3];
        const int rl = tid >> 4, j = tid & 15;
        const int r = row0m + rl;
        const int act = actP[r];
        float dh = fmaxf(dhpP[(size_t)r * 32 + j], dhpP[(size_t)r * 32 + 16 + j]);
        float M1 = m1p[(size_t)r * 16 + j], M2 = m2p[(size_t)r * 16 + j];
#pragma unroll
        for (int off = 1; off < 16; off <<= 1) {
            dh = fmaxf(dh, __shfl_xor(dh, off));
            float o1 = __shfl_xor(M1, off), o2 = __shfl_xor(M2, off);
            if (o1 > M1) { M2 = fmaxf(M1, o2); M1 = o1; }
            else M2 = fmaxf(M2, o1);
        }
        if (j == 0) {
            int nw = act && ((M1 - M2) > gamma2 * dh);
            snew[rl] = nw;
            sact[rl] = act && !nw;
        }
    } else if (tid < 64) {
        sact[tid] = 1; snew[tid] = 0;
    }
    __syncthreads();
    if (tid < 64) {
        unsigned long long b = __ballot(sact[tid] != 0);
        actC[row0m + tid] = sact[tid];              // identical across the 32 sibling blocks
        if (tid == 0) {
            s_cnt = __popcll(b);
            (cnt + pc * 8)[rt] = s_cnt;             // identical across siblings
        }
    }
    // newly certified rows -> out (one designated block per row-tile)
    if (t > 1 && (bid & 31) == 0) {
        for (int rl2 = 0; rl2 < 64; ++rl2) {
            if (snew[rl2]) {
                const float* lr = logits + (size_t)(row0m + rl2) * LD;
                float* orow = out + (size_t)(row0m + rl2) * LD;
                for (int jj = tid; jj < LD; jj += 1024) orow[jj] = lr[jj];
            }
        }
    }
    __syncthreads();
    if (s_cnt == 0) return;

    // ---- P1 GEMM ----
    f32x4 acc;
    tile64_gemm<false>(nullptr, Hshi, Hslo, HDm, row0m, WHThi, WHTlo, HDm, col0, HDm, lds, acc);
    const int lane = tid & 63, w = tid >> 6;
    const int gc = col0 + (w & 3) * 16 + (lane & 15);
    const int gr0 = row0m + (w >> 2) * 16 + ((lane >> 4) << 2);
    float dh4[4];
#pragma unroll
    for (int r = 0; r < 4; ++r) {
        const int gr = gr0 + r;
        const size_t idx = (size_t)gr * HDm + gc;
        const unsigned short oh = Hshi[idx], ol = Hslo[idx];
        const float old = bf2f(oh) + bf2f(ol);
        const int a = sact[gr - row0m];
        unsigned short nh, nl;
        if (a) {
            const float pre = acc[r] + drive[idx];
            const float av = pre >= 0.f ? pre : ALPHAc * pre;
            split2(av, nh, nl);
        } else { nh = oh; nl = ol; }
        Hnhi[idx] = nh; Hnlo[idx] = nl;
        dh4[r] = fabsf((bf2f(nh) + bf2f(nl)) - old);   // exactly 0 for frozen rows
    }
#pragma unroll
    for (int off = 1; off < 16; off <<= 1)
#pragma unroll
        for (int r = 0; r < 4; ++r)
            dh4[r] = fmaxf(dh4[r], __shfl_xor(dh4[r], off));
    __syncthreads();
    float (*sdh)[4] = (float(*)[4])lds;
    if ((lane & 15) == 0) {
        const int rl0 = (w >> 2) * 16 + ((lane >> 4) << 2);
#pragma unroll
        for (int r = 0; r < 4; ++r) sdh[rl0 + r][w & 3] = dh4[r];
    }
    __syncthreads();
    if (tid < 64) {
        float d = fmaxf(fmaxf(sdh[tid][0], sdh[tid][1]),
                        fmaxf(sdh[tid][2], sdh[tid][3]));
        dhpC[(size_t)(row0m + tid) * 32 + (bid & 31)] = d;
    }
}

// ---------------------------------------------------------------------------
// k_p2(t): logits = Hn @ W_HL + BL + top2 partials (skips frozen row-tiles)
// ---------------------------------------------------------------------------
__global__ __launch_bounds__(1024) void k_p2(
    const unsigned short* __restrict__ WHLThi, const unsigned short* __restrict__ WHLTlo,
    const float* __restrict__ BL,
    const unsigned short* __restrict__ HAhi, const unsigned short* __restrict__ HAlo,
    const unsigned short* __restrict__ HBhi, const unsigned short* __restrict__ HBlo,
    float* __restrict__ logits, const int* __restrict__ active, const int* __restrict__ cnt,
    float* __restrict__ m1p, float* __restrict__ m2p, int t)
{
    __shared__ char lds[49152];
    __shared__ int s_any;
    const int pc = t & 1;
    {
        const int* cp = cnt + pc * 8;
        int sum = 0;
#pragma unroll
        for (int i = 0; i < 8; ++i) sum += cp[i];
        if (sum == 0) return;
    }
    const int bid = blockIdx.x, tid = threadIdx.x;
    const unsigned short* Hnhi = (t & 1) ? HBhi : HAhi;
    const unsigned short* Hnlo = (t & 1) ? HBlo : HAlo;
    const int* actC = active + pc * BN;
    const int row0 = (bid >> 4) * 32, col0 = (bid & 15) * 64;

    if (tid < 64) {
        int a = (tid < 32) ? actC[row0 + tid] : 0;
        unsigned long long bl = __ballot(a != 0);
        if (tid == 0) s_any = (bl != 0ull);
    }
    __syncthreads();
    if (!s_any) return;

    f32x4 acc;
    int s, p;
    tile32_gemm_ks(Hnhi, Hnlo, row0, WHLThi, WHLTlo, col0, lds, acc, s, p);
    const int lane = tid & 63;
    f32x4* red = (f32x4*)lds;
    float (*st1)[4] = (float(*)[4])(lds + 36864);
    float (*st2)[4] = (float(*)[4])(lds + 37888);
    __syncthreads();
    if (p == 1) red[s * 64 + lane] = acc;
    __syncthreads();
    if (p == 0) {
        f32x4 o = red[s * 64 + lane];
        const int gc = col0 + (s & 3) * 16 + (lane & 15);
        const int gr0 = row0 + (s >> 2) * 16 + ((lane >> 4) << 2);
        const bool okc = gc < LD;
        const float blv = okc ? BL[gc] : 0.f;
        float m1a[4], m2a[4];
#pragma unroll
        for (int r = 0; r < 4; ++r) {
            const float v = acc[r] + o[r] + blv;
            if (okc) logits[(size_t)(gr0 + r) * LD + gc] = v;
            m1a[r] = okc ? v : -3.4e38f;
            m2a[r] = -3.4e38f;
        }
#pragma unroll
        for (int off = 1; off < 16; off <<= 1) {
#pragma unroll
            for (int r = 0; r < 4; ++r) {
                float o1 = __shfl_xor(m1a[r], off);
                float o2 = __shfl_xor(m2a[r], off);
                if (o1 > m1a[r]) { m2a[r] = fmaxf(m1a[r], o2); m1a[r] = o1; }
                else m2a[r] = fmaxf(m2a[r], o1);
            }
        }
        if ((lane & 15) == 0) {
            const int rl0 = (s >> 2) * 16 + ((lane >> 4) << 2);
#pragma unroll
            for (int r = 0; r < 4; ++r) {
                st1[rl0 + r][s & 3] = m1a[r];
                st2[rl0 + r][s & 3] = m2a[r];
            }
        }
    }
    __syncthreads();
    if (tid < 32) {
        float M1 = st1[tid][0], M2 = st2[tid][0];
#pragma unroll
        for (int g = 1; g < 4; ++g) {
            float o1 = st1[tid][g], o2 = st2[tid][g];
            if (o1 > M1) { M2 = fmaxf(M1, o2); M1 = o1; }
            else M2 = fmaxf(M2, o1);
        }
        m1p[(size_t)(row0 + tid) * 16 + (bid & 15)] = M1;
        m2p[(size_t)(row0 + tid) * 16 + (bid & 15)] = M2;
    }
}

// rows never finalized-certified take the last-step logits (row active in
// BOTH parities; re-copies of just-certified rows are identical values)
__global__ __launch_bounds__(1024) void k_tail(
    const float* __restrict__ logits, const int* __restrict__ active,
    float* __restrict__ out)
{
    const int row0 = blockIdx.x * 64;
    for (int rl = 0; rl < 64; ++rl) {
        const int r = row0 + rl;
        if (active[r] && active[BN + r]) {
            const float* lr = logits + (size_t)r * LD;
            float* orow = out + (size_t)r * LD;
            for (int jj = threadIdx.x; jj < LD; jj += 1024) orow[jj] = lr[jj];
        }
    }
}

// ---------------------------------------------------------------------------
extern "C" void kernel_launch(void* const* d_in, const int* in_sizes, int n_in,
                              void* d_out, int out_size, void* d_ws, size_t ws_size,
                              hipStream_t stream)
{
    const float* x   = (const float*)d_in[0];
    const float* RIH = (const float*)d_in[1];
    const float* RH  = (const float*)d_in[2];
    const float* RHL = (const float*)d_in[3];
    const float* BH  = (const float*)d_in[4];
    const float* BL  = (const float*)d_in[5];
    const float* MIH = (const float*)d_in[6];
    const float* MH  = (const float*)d_in[7];
    const float* MHL = (const float*)d_in[8];
    float* out = (float*)d_out;
    char* w = (char*)d_ws;

    unsigned short* WHThi = (unsigned short*)(w);                 //  8 MB
    unsigned short* WHTlo = (unsigned short*)(w + 8388608);       //  8 MB
    unsigned short* WXhi  = (unsigned short*)(w + 16777216);      //  4 MB (W_IH^T then W_HL^T)
    unsigned short* WXlo  = (unsigned short*)(w + 20971520);      //  4 MB
    float* drive  = (float*)(w + 25165824);                       //  4 MB
    unsigned short* HAhi = (unsigned short*)(w + 29360128);       //  2 MB
    unsigned short* HAlo = (unsigned short*)(w + 31457280);       //  2 MB
    unsigned short* HBhi = (unsigned short*)(w + 33554432);       //  2 MB
    unsigned short* HBlo = (unsigned short*)(w + 35651584);       //  2 MB
    float* logits = (float*)(w + 37748736);                       //  2 MB
    float* scal   = (float*)(w + 39845888);                       //  8 f
    int*   active = (int*)(w + 39845920);                         //  2 x 512
    int*   cnt    = (int*)(w + 39850016);                         //  2 x 8
    float* dhp    = (float*)(w + 39850080);                       //  2 x 512 x 32 = 128 KB
    float* m1p    = (float*)(w + 39981152);                       //  32 KB
    float* m2p    = (float*)(w + 40013920);                       //  32 KB

    k_init<<<4, 256, 0, stream>>>(active, cnt, scal);
    k_colsum_wh<<<256, 256, 0, stream>>>(RH, MH, dhp);            // dhp reused as part_wh
    k_colsum_whl<<<128, 256, 0, stream>>>(RHL, MHL, m1p);         // m1p reused as part_whl
    k_scalars<<<1, 1024, 0, stream>>>(dhp, m1p, scal);
    k_wsplit<<<512, 256, 0, stream>>>(RIH, MIH, WXhi, WXlo, ID, HDm, HDm, scal, -1);
    k_drive_mfma<<<256, 1024, 0, stream>>>(x, WXhi, WXlo, BH, drive);
    k_wsplit<<<1024, 256, 0, stream>>>(RH, MH, WHThi, WHTlo, HDm, HDm, HDm, scal, 2);
    k_wsplit<<<512, 256, 0, stream>>>(RHL, MHL, WXhi, WXlo, HDm, LD, 1024, scal, -1);
    (void)hipMemsetAsync(HAhi, 0, 4194304, stream);   // zeros HAhi + HAlo (contiguous)

    for (int t = 1; t <= TMAXc; ++t) {
        k_p1<<<256, 1024, 0, stream>>>(WHThi, WHTlo, drive, HAhi, HAlo, HBhi, HBlo,
                                       logits, out, active, cnt, scal, dhp, m1p, m2p, t);
        k_p2<<<256, 1024, 0, stream>>>(WXhi, WXlo, BL, HAhi, HAlo, HBhi, HBlo,
                                       logits, active, cnt, m1p, m2p, t);
    }
    k_tail<<<8, 1024, 0, stream>>>(logits, active, out);
}

// Round 11
// 1517.964 us; speedup vs baseline: 8.9520x; 1.1396x over previous
//
#include <hip/hip_runtime.h>

typedef __attribute__((ext_vector_type(8))) short short8;
typedef __attribute__((ext_vector_type(4))) float f32x4;

static constexpr int BN    = 512;
static constexpr int ID    = 1024;
static constexpr int HDm   = 2048;
static constexpr int LD    = 1000;
static constexpr int TMAXc = 32;
static constexpr float ALPHAc = 0.05f;

// ---------------- bf16 split helpers (x ~= hi + lo, each bf16) ----------------
__device__ __forceinline__ unsigned short f2bf(float x) {
    unsigned u = __float_as_uint(x);
    u += 0x7fffu + ((u >> 16) & 1u);           // RNE
    return (unsigned short)(u >> 16);
}
__device__ __forceinline__ float bf2f(unsigned short h) {
    return __uint_as_float(((unsigned)h) << 16);
}
__device__ __forceinline__ void split2(float x, unsigned short& hi, unsigned short& lo) {
    hi = f2bf(x);
    lo = f2bf(x - bf2f(hi));
}

// ---------------------------------------------------------------------------
// 64x32 tile, K-chunk 128, 1024 threads: 8 fragments (4 frow x 2 fcol) x
// 2-way K-split (p = wave>>3). 2-deep prefetch, split-bf16 3-term MFMA.
// LDS: Ah 16K | Al 16K | Bh 8K | Bl 8K = 48 KB. Swizzle: byte ^= (row&15)<<4.
// ---------------------------------------------------------------------------
template<bool SPLITA>
__device__ __forceinline__ void tile64x32(
    const float* __restrict__ Af,
    const unsigned short* __restrict__ Ahi, const unsigned short* __restrict__ Alo,
    int lda, int row0,
    const unsigned short* __restrict__ BThi, const unsigned short* __restrict__ BTlo,
    int ldk, int col0, int K, char* lds, f32x4& acc, int& s_out, int& p_out)
{
    char* Ah = lds;
    char* Al = lds + 16384;
    char* Bh = lds + 32768;
    char* Bl = lds + 40960;
    const int t = threadIdx.x, lane = t & 63, w = t >> 6;
    const int s = w & 7, p = w >> 3;
    s_out = s; p_out = p;
    f32x4 z = {0.f, 0.f, 0.f, 0.f};
    acc = z;

    const int ar = t >> 4, ac = (t & 15) << 3;     // A: 64 rows x 128, 8 elems/stream
    const int br = t >> 5, bc = (t & 31) << 2;     // B: 32 rows x 128, 4 elems/stream
    const int asb = (ar * 256 + ac * 2) ^ ((ar & 15) << 4);
    const int bsb = (br * 256 + bc * 2) ^ ((br & 15) << 4);
    const float* Ap = SPLITA ? (Af + (size_t)(row0 + ar) * lda + ac) : nullptr;
    const unsigned short* Ahp = SPLITA ? nullptr : (Ahi + (size_t)(row0 + ar) * lda + ac);
    const unsigned short* Alp = SPLITA ? nullptr : (Alo + (size_t)(row0 + ar) * lda + ac);
    const unsigned short* Bhp = BThi + (size_t)(col0 + br) * ldk + bc;
    const unsigned short* Blp = BTlo + (size_t)(col0 + br) * ldk + bc;

    const int frow = s >> 1, fcol = s & 1;
    const int arow = frow * 16 + (lane & 15);
    const int colr = fcol * 16 + (lane & 15);
    const int ab0 = arow * 256, bb0 = colr * 256;
    const int axor = (arow & 15) << 4, bxor = (colr & 15) << 4;
    const int kwin = p * 128 + ((lane >> 4) << 4);

    float4 af0a, af0b, af1a, af1b;
    uint4 ah0, al0, ah1, al1;
    if constexpr (SPLITA) {
        af0a = *(const float4*)(Ap);       af0b = *(const float4*)(Ap + 4);
        af1a = *(const float4*)(Ap + 128); af1b = *(const float4*)(Ap + 132);
    } else {
        ah0 = *(const uint4*)(Ahp);       al0 = *(const uint4*)(Alp);
        ah1 = *(const uint4*)(Ahp + 128); al1 = *(const uint4*)(Alp + 128);
    }
    uint2 bh0 = *(const uint2*)(Bhp),       bl0 = *(const uint2*)(Blp);
    uint2 bh1 = *(const uint2*)(Bhp + 128), bl1 = *(const uint2*)(Blp + 128);

    for (int k0 = 0; k0 < K; k0 += 128) {
        uint4 awh, awl;
        if constexpr (SPLITA) {
            unsigned short h[8], l[8];
            const float vv[8] = {af0a.x, af0a.y, af0a.z, af0a.w,
                                 af0b.x, af0b.y, af0b.z, af0b.w};
#pragma unroll
            for (int i = 0; i < 8; ++i) split2(vv[i], h[i], l[i]);
            awh = make_uint4((unsigned)h[0] | ((unsigned)h[1] << 16),
                             (unsigned)h[2] | ((unsigned)h[3] << 16),
                             (unsigned)h[4] | ((unsigned)h[5] << 16),
                             (unsigned)h[6] | ((unsigned)h[7] << 16));
            awl = make_uint4((unsigned)l[0] | ((unsigned)l[1] << 16),
                             (unsigned)l[2] | ((unsigned)l[3] << 16),
                             (unsigned)l[4] | ((unsigned)l[5] << 16),
                             (unsigned)l[6] | ((unsigned)l[7] << 16));
        } else { awh = ah0; awl = al0; }
        const uint2 bwh = bh0, bwl = bl0;
        __syncthreads();                            // prior LDS readers done
        *(uint4*)(Ah + asb) = awh;
        *(uint4*)(Al + asb) = awl;
        *(uint2*)(Bh + bsb) = bwh;
        *(uint2*)(Bl + bsb) = bwl;
        if constexpr (SPLITA) { af0a = af1a; af0b = af1b; } else { ah0 = ah1; al0 = al1; }
        bh0 = bh1; bl0 = bl1;
        if (k0 + 256 < K) {
            if constexpr (SPLITA) {
                af1a = *(const float4*)(Ap + k0 + 256);
                af1b = *(const float4*)(Ap + k0 + 260);
            } else {
                ah1 = *(const uint4*)(Ahp + k0 + 256);
                al1 = *(const uint4*)(Alp + k0 + 256);
            }
            bh1 = *(const uint2*)(Bhp + k0 + 256);
            bl1 = *(const uint2*)(Blp + k0 + 256);
        }
        __syncthreads();
#pragma unroll
        for (int ks = 0; ks < 2; ++ks) {
            const int kb = kwin + ks * 64;
            short8 bh = *(const short8*)(Bh + ((bb0 + kb) ^ bxor));
            short8 bl = *(const short8*)(Bl + ((bb0 + kb) ^ bxor));
            short8 ah = *(const short8*)(Ah + ((ab0 + kb) ^ axor));
            short8 al = *(const short8*)(Al + ((ab0 + kb) ^ axor));
            acc = __builtin_amdgcn_mfma_f32_16x16x32_bf16(ah, bh, acc, 0, 0, 0);
            acc = __builtin_amdgcn_mfma_f32_16x16x32_bf16(al, bh, acc, 0, 0, 0);
            acc = __builtin_amdgcn_mfma_f32_16x16x32_bf16(ah, bl, acc, 0, 0, 0);
        }
    }
}

// ---------------------------------------------------------------------------
// 32x32 tile, K-chunk 128, 1024 threads: 4 fragments x 4-way K-split (p=w>>2).
// LDS: Ah 8K | Al 8K | Bh 8K | Bl 8K = 32 KB (+12 KB reduce region after).
// ---------------------------------------------------------------------------
__device__ __forceinline__ void tile32x32(
    const unsigned short* __restrict__ Ahi, const unsigned short* __restrict__ Alo, int row0,
    const unsigned short* __restrict__ BThi, const unsigned short* __restrict__ BTlo,
    int col0, char* lds, f32x4& acc, int& s_out, int& p_out)
{
    char* Ah = lds;
    char* Al = lds + 8192;
    char* Bh = lds + 16384;
    char* Bl = lds + 24576;
    const int t = threadIdx.x, lane = t & 63, w = t >> 6;
    const int s = w & 3, p = w >> 2;
    s_out = s; p_out = p;
    f32x4 z = {0.f, 0.f, 0.f, 0.f};
    acc = z;

    const int ar = t >> 5, ac = (t & 31) << 2;     // 32 rows x 128, 4 elems/stream
    const int asb = (ar * 256 + ac * 2) ^ ((ar & 15) << 4);
    const unsigned short* Ahp = Ahi + (size_t)(row0 + ar) * HDm + ac;
    const unsigned short* Alp = Alo + (size_t)(row0 + ar) * HDm + ac;
    const unsigned short* Bhp = BThi + (size_t)(col0 + ar) * HDm + ac;
    const unsigned short* Blp = BTlo + (size_t)(col0 + ar) * HDm + ac;

    const int frow = s >> 1, fcol = s & 1;
    const int arow = frow * 16 + (lane & 15);
    const int colr = fcol * 16 + (lane & 15);
    const int ab0 = arow * 256, bb0 = colr * 256;
    const int axor = (arow & 15) << 4, bxor = (colr & 15) << 4;
    const int kwin = p * 64 + ((lane >> 4) << 4);

    uint2 ah0 = *(const uint2*)(Ahp),       al0 = *(const uint2*)(Alp);
    uint2 bh0 = *(const uint2*)(Bhp),       bl0 = *(const uint2*)(Blp);
    uint2 ah1 = *(const uint2*)(Ahp + 128), al1 = *(const uint2*)(Alp + 128);
    uint2 bh1 = *(const uint2*)(Bhp + 128), bl1 = *(const uint2*)(Blp + 128);

    for (int k0 = 0; k0 < HDm; k0 += 128) {
        const uint2 awh = ah0, awl = al0, bwh = bh0, bwl = bl0;
        __syncthreads();
        *(uint2*)(Ah + asb) = awh;
        *(uint2*)(Al + asb) = awl;
        *(uint2*)(Bh + asb) = bwh;
        *(uint2*)(Bl + asb) = bwl;
        ah0 = ah1; al0 = al1; bh0 = bh1; bl0 = bl1;
        if (k0 + 256 < HDm) {
            ah1 = *(const uint2*)(Ahp + k0 + 256);
            al1 = *(const uint2*)(Alp + k0 + 256);
            bh1 = *(const uint2*)(Bhp + k0 + 256);
            bl1 = *(const uint2*)(Blp + k0 + 256);
        }
        __syncthreads();
        const int kb = kwin;
        short8 bh = *(const short8*)(Bh + ((bb0 + kb) ^ bxor));
        short8 bl = *(const short8*)(Bl + ((bb0 + kb) ^ bxor));
        short8 ah = *(const short8*)(Ah + ((ab0 + kb) ^ axor));
        short8 al = *(const short8*)(Al + ((ab0 + kb) ^ axor));
        acc = __builtin_amdgcn_mfma_f32_16x16x32_bf16(ah, bh, acc, 0, 0, 0);
        acc = __builtin_amdgcn_mfma_f32_16x16x32_bf16(al, bh, acc, 0, 0, 0);
        acc = __builtin_amdgcn_mfma_f32_16x16x32_bf16(ah, bl, acc, 0, 0, 0);
    }
}

// ---------------------------------------------------------------------------
// Prep kernels
// ---------------------------------------------------------------------------
__global__ void k_init(int* active, int* cnt, float* scal)
{
    int i = blockIdx.x * blockDim.x + threadIdx.x;
    if (i < 2 * BN) active[i] = 1;
    if (i < 16) cnt[i] = 64;
    if (i < 8) scal[i] = 0.f;
}

__global__ __launch_bounds__(256) void k_colsum_wh(const float* __restrict__ RH,
                                                   const float* __restrict__ MH,
                                                   float* __restrict__ part)
{
    const int colTile = blockIdx.x >> 3, rs = blockIdx.x & 7;
    const int col = colTile * 64 + (threadIdx.x & 63);
    const int rq = threadIdx.x >> 6;
    const int r0 = rs * 256;
    float s = 0.f;
    for (int i = r0 + rq; i < r0 + 256; i += 4)
        s += fabsf(RH[(size_t)i * HDm + col] * MH[(size_t)i * HDm + col]);
    __shared__ float red[4][64];
    red[rq][threadIdx.x & 63] = s;
    __syncthreads();
    if (threadIdx.x < 64)
        part[(size_t)rs * HDm + col] = red[0][threadIdx.x] + red[1][threadIdx.x] +
                                       red[2][threadIdx.x] + red[3][threadIdx.x];
}

__global__ __launch_bounds__(256) void k_colsum_whl(const float* __restrict__ RHL,
                                                    const float* __restrict__ MHL,
                                                    float* __restrict__ part)
{
    const int colTile = blockIdx.x >> 3, rs = blockIdx.x & 7;
    const int col = colTile * 64 + (threadIdx.x & 63);
    const int rq = threadIdx.x >> 6;
    const int r0 = rs * 256;
    float s = 0.f;
    if (col < LD) {
        for (int i = r0 + rq; i < r0 + 256; i += 4)
            s += fabsf(RHL[(size_t)i * LD + col] * MHL[(size_t)i * LD + col]);
    }
    __shared__ float red[4][64];
    red[rq][threadIdx.x & 63] = s;
    __syncthreads();
    if (threadIdx.x < 64)
        part[(size_t)rs * 1024 + col] = red[0][threadIdx.x] + red[1][threadIdx.x] +
                                        red[2][threadIdx.x] + red[3][threadIdx.x];
}

__global__ __launch_bounds__(1024) void k_scalars(const float* __restrict__ part_wh,
                                                  const float* __restrict__ part_whl,
                                                  float* scal)
{
    float m1 = 0.f, m2 = 0.f;
    for (int c = threadIdx.x; c < HDm; c += 1024) {
        float s = 0.f;
#pragma unroll
        for (int k = 0; k < 8; ++k) s += part_wh[(size_t)k * HDm + c];
        m1 = fmaxf(m1, s);
    }
    {
        const int c = threadIdx.x;
        if (c < 1024) {
            float s = 0.f;
#pragma unroll
            for (int k = 0; k < 8; ++k) s += part_whl[(size_t)k * 1024 + c];
            m2 = fmaxf(m2, s);
        }
    }
#pragma unroll
    for (int off = 1; off < 64; off <<= 1) {
        m1 = fmaxf(m1, __shfl_xor(m1, off));
        m2 = fmaxf(m2, __shfl_xor(m2, off));
    }
    __shared__ float r1[16], r2[16];
    if ((threadIdx.x & 63) == 0) { r1[threadIdx.x >> 6] = m1; r2[threadIdx.x >> 6] = m2; }
    __syncthreads();
    if (threadIdx.x == 0) {
        float a = 0.f, b = 0.f;
#pragma unroll
        for (int i = 0; i < 16; ++i) { a = fmaxf(a, r1[i]); b = fmaxf(b, r2[i]); }
        scal[2] = 0.95f / fmaxf(a, 1e-8f);
        scal[3] = b * 19.f;
    }
}

// Transposed split:  O{hi,lo}[c][r] = split(R[r][c] * M[r][c] * s)
__global__ __launch_bounds__(256) void k_wsplit(
    const float* __restrict__ R, const float* __restrict__ M,
    unsigned short* __restrict__ Ohi, unsigned short* __restrict__ Olo,
    int NR, int NC, int NCp, const float* __restrict__ scal, int scidx)
{
    __shared__ float T[64][65];
    const int nct = NCp >> 6;
    const int c0 = (blockIdx.x % nct) << 6;
    const int r0 = (blockIdx.x / nct) << 6;
    const float s = (scidx >= 0) ? scal[scidx] : 1.f;
    const int t = threadIdx.x;
    const int ir = t >> 2, ics = (t & 3) << 4;
#pragma unroll
    for (int i = 0; i < 16; ++i) {
        const int c = c0 + ics + i;
        float v = 0.f;
        if (c < NC) {
            const size_t idx = (size_t)(r0 + ir) * NC + c;
            v = R[idx] * M[idx] * s;
        }
        T[ir][ics + i] = v;
    }
    __syncthreads();
    const int oc = t >> 2, ors = (t & 3) << 4;
    unsigned short hb[16], lb[16];
#pragma unroll
    for (int i = 0; i < 16; ++i) split2(T[ors + i][oc], hb[i], lb[i]);
    const size_t base = (size_t)(c0 + oc) * NR + r0 + ors;
    uint4 v;
    v.x = hb[0] | ((unsigned)hb[1] << 16);  v.y = hb[2] | ((unsigned)hb[3] << 16);
    v.z = hb[4] | ((unsigned)hb[5] << 16);  v.w = hb[6] | ((unsigned)hb[7] << 16);
    *(uint4*)(Ohi + base) = v;
    v.x = hb[8] | ((unsigned)hb[9] << 16);  v.y = hb[10] | ((unsigned)hb[11] << 16);
    v.z = hb[12] | ((unsigned)hb[13] << 16); v.w = hb[14] | ((unsigned)hb[15] << 16);
    *(uint4*)(Ohi + base + 8) = v;
    v.x = lb[0] | ((unsigned)lb[1] << 16);  v.y = lb[2] | ((unsigned)lb[3] << 16);
    v.z = lb[4] | ((unsigned)lb[5] << 16);  v.w = lb[6] | ((unsigned)lb[7] << 16);
    *(uint4*)(Olo + base) = v;
    v.x = lb[8] | ((unsigned)lb[9] << 16);  v.y = lb[10] | ((unsigned)lb[11] << 16);
    v.z = lb[12] | ((unsigned)lb[13] << 16); v.w = lb[14] | ((unsigned)lb[15] << 16);
    *(uint4*)(Olo + base + 8) = v;
}

// drive = x @ W_IH + BH   (512 blocks = 8 x 64 tiles of 64x32, K=1024)
__global__ __launch_bounds__(1024, 8) void k_drive_mfma(
    const float* __restrict__ x,
    const unsigned short* __restrict__ WIHThi, const unsigned short* __restrict__ WIHTlo,
    const float* __restrict__ BH, float* __restrict__ drive)
{
    __shared__ char lds[49152];
    f32x4 acc;
    int s, p;
    const int row0 = (blockIdx.x >> 6) * 64, col0 = (blockIdx.x & 63) * 32;
    tile64x32<true>(x, nullptr, nullptr, ID, row0, WIHThi, WIHTlo, ID, col0, ID,
                    lds, acc, s, p);
    const int lane = threadIdx.x & 63;
    __syncthreads();
    f32x4* red = (f32x4*)lds;
    if (p == 1) red[s * 64 + lane] = acc;
    __syncthreads();
    if (p == 0) {
        f32x4 o = red[s * 64 + lane];
        acc += o;
        const int frow = s >> 1, fcol = s & 1;
        const int gc = col0 + fcol * 16 + (lane & 15);
        const int gr0 = row0 + frow * 16 + ((lane >> 4) << 2);
        const float bh = BH[gc];
#pragma unroll
        for (int r = 0; r < 4; ++r)
            drive[(size_t)(gr0 + r) * HDm + gc] = acc[r] + bh;
    }
}

// ---------------------------------------------------------------------------
// k_p1(t): finalize(t-1) from parity-(t-1) partials, then
//          Hn = select(active, LeakyReLU(Hs@W_H + drive), Hs) + dH partials.
// Grid 512 = 8 row-tiles(64) x 64 col-tiles(32).
// ---------------------------------------------------------------------------
__global__ __launch_bounds__(1024, 8) void k_p1(
    const unsigned short* __restrict__ WHThi, const unsigned short* __restrict__ WHTlo,
    const float* __restrict__ drive,
    unsigned short* __restrict__ HAhi, unsigned short* __restrict__ HAlo,
    unsigned short* __restrict__ HBhi, unsigned short* __restrict__ HBlo,
    const float* __restrict__ logits, float* __restrict__ out,
    int* __restrict__ active, int* __restrict__ cnt, const float* __restrict__ scal,
    float* __restrict__ dhp, const float* __restrict__ m1p, const float* __restrict__ m2p,
    int t)
{
    __shared__ char lds[49152];
    __shared__ int sact[64], snew[64];
    __shared__ int s_cnt;
    const int pp = (t - 1) & 1, pc = t & 1;
    {   // frozen early-exit gate (written by p1(t-1) only)
        const int* cp = cnt + pp * 8;
        int sum = 0;
#pragma unroll
        for (int i = 0; i < 8; ++i) sum += cp[i];
        if (sum == 0) return;
    }
    const int bid = blockIdx.x, tid = threadIdx.x;
    const int rt = bid >> 6, row0m = rt << 6, col0 = (bid & 63) * 32;
    const int* actP = active + pp * BN;
    int* actC = active + pc * BN;
    const unsigned short* Hshi = (t & 1) ? HAhi : HBhi;
    const unsigned short* Hslo = (t & 1) ? HAlo : HBlo;
    unsigned short* Hnhi = (t & 1) ? HBhi : HAhi;
    unsigned short* Hnlo = (t & 1) ? HBlo : HAlo;
    const float* dhpP = dhp + (size_t)pp * BN * 64;
    float* dhpC = dhp + (size_t)pc * BN * 64;

    // ---- finalize(t-1): certification from frozen partials ----
    if (t > 1) {
        const float gamma2 = 2.f * scal[3];
        const int rl = tid >> 4, j = tid & 15;
        const int r = row0m + rl;
        const int act = actP[r];
        float dh = fmaxf(fmaxf(dhpP[(size_t)r * 64 + j],      dhpP[(size_t)r * 64 + 16 + j]),
                         fmaxf(dhpP[(size_t)r * 64 + 32 + j], dhpP[(size_t)r * 64 + 48 + j]));
        float M1 = m1p[(size_t)r * 32 + j], M2 = m2p[(size_t)r * 32 + j];
        {
            float o1 = m1p[(size_t)r * 32 + 16 + j], o2 = m2p[(size_t)r * 32 + 16 + j];
            if (o1 > M1) { M2 = fmaxf(M1, o2); M1 = o1; }
            else M2 = fmaxf(M2, o1);
        }
#pragma unroll
        for (int off = 1; off < 16; off <<= 1) {
            dh = fmaxf(dh, __shfl_xor(dh, off));
            float o1 = __shfl_xor(M1, off), o2 = __shfl_xor(M2, off);
            if (o1 > M1) { M2 = fmaxf(M1, o2); M1 = o1; }
            else M2 = fmaxf(M2, o1);
        }
        if (j == 0) {
            int nw = act && ((M1 - M2) > gamma2 * dh);
            snew[rl] = nw;
            sact[rl] = act && !nw;
        }
    } else if (tid < 64) {
        sact[tid] = 1; snew[tid] = 0;
    }
    __syncthreads();
    if (tid < 64) {
        unsigned long long b = __ballot(sact[tid] != 0);
        actC[row0m + tid] = sact[tid];              // identical across 64 sibling blocks
        if (tid == 0) {
            s_cnt = __popcll(b);
            (cnt + pc * 8)[rt] = s_cnt;             // identical across siblings
        }
    }
    // newly certified rows -> out (one designated block per row-tile)
    if (t > 1 && (bid & 63) == 0) {
        for (int rl2 = 0; rl2 < 64; ++rl2) {
            if (snew[rl2]) {
                const float* lr = logits + (size_t)(row0m + rl2) * LD;
                float* orow = out + (size_t)(row0m + rl2) * LD;
                for (int jj = tid; jj < LD; jj += 1024) orow[jj] = lr[jj];
            }
        }
    }
    __syncthreads();
    if (s_cnt == 0) return;

    // ---- P1 GEMM ----
    f32x4 acc;
    int s, p;
    tile64x32<false>(nullptr, Hshi, Hslo, HDm, row0m, WHThi, WHTlo, HDm, col0, HDm,
                     lds, acc, s, p);
    const int lane = tid & 63;
    __syncthreads();
    f32x4* red = (f32x4*)lds;
    if (p == 1) red[s * 64 + lane] = acc;
    __syncthreads();
    float (*sdh)[2] = (float(*)[2])(lds + 16384);
    if (p == 0) {
        f32x4 o = red[s * 64 + lane];
        acc += o;
        const int frow = s >> 1, fcol = s & 1;
        const int gc = col0 + fcol * 16 + (lane & 15);
        const int gr0 = row0m + frow * 16 + ((lane >> 4) << 2);
        float dh4[4];
#pragma unroll
        for (int r = 0; r < 4; ++r) {
            const int gr = gr0 + r;
            const size_t idx = (size_t)gr * HDm + gc;
            const unsigned short oh = Hshi[idx], ol = Hslo[idx];
            const float old = bf2f(oh) + bf2f(ol);
            const int a = sact[gr - row0m];
            unsigned short nh, nl;
            if (a) {
                const float pre = acc[r] + drive[idx];
                const float av = pre >= 0.f ? pre : ALPHAc * pre;
                split2(av, nh, nl);
            } else { nh = oh; nl = ol; }
            Hnhi[idx] = nh; Hnlo[idx] = nl;
            dh4[r] = fabsf((bf2f(nh) + bf2f(nl)) - old);   // exactly 0 for frozen rows
        }
#pragma unroll
        for (int off = 1; off < 16; off <<= 1)
#pragma unroll
            for (int r = 0; r < 4; ++r)
                dh4[r] = fmaxf(dh4[r], __shfl_xor(dh4[r], off));
        if ((lane & 15) == 0) {
            const int rl0 = frow * 16 + ((lane >> 4) << 2);
#pragma unroll
            for (int r = 0; r < 4; ++r) sdh[rl0 + r][fcol] = dh4[r];
        }
    }
    __syncthreads();
    if (tid < 64) {
        float d = fmaxf(sdh[tid][0], sdh[tid][1]);
        dhpC[(size_t)(row0m + tid) * 64 + (bid & 63)] = d;
    }
}

// ---------------------------------------------------------------------------
// k_p2(t): logits = Hn @ W_HL + BL + top2 partials.
// Grid 512 = 16 row-tiles(32) x 32 col-tiles(32).
// ---------------------------------------------------------------------------
__global__ __launch_bounds__(1024, 8) void k_p2(
    const unsigned short* __restrict__ WHLThi, const unsigned short* __restrict__ WHLTlo,
    const float* __restrict__ BL,
    const unsigned short* __restrict__ HAhi, const unsigned short* __restrict__ HAlo,
    const unsigned short* __restrict__ HBhi, const unsigned short* __restrict__ HBlo,
    float* __restrict__ logits, const int* __restrict__ active, const int* __restrict__ cnt,
    float* __restrict__ m1p, float* __restrict__ m2p, int t)
{
    __shared__ char lds[46080];
    __shared__ int s_any;
    const int pc = t & 1;
    {
        const int* cp = cnt + pc * 8;
        int sum = 0;
#pragma unroll
        for (int i = 0; i < 8; ++i) sum += cp[i];
        if (sum == 0) return;
    }
    const int bid = blockIdx.x, tid = threadIdx.x;
    const unsigned short* Hnhi = (t & 1) ? HBhi : HAhi;
    const unsigned short* Hnlo = (t & 1) ? HBlo : HAlo;
    const int* actC = active + pc * BN;
    const int row0 = (bid >> 5) * 32, col0 = (bid & 31) * 32;

    if (tid < 64) {
        int a = (tid < 32) ? actC[row0 + tid] : 0;
        unsigned long long bl = __ballot(a != 0);
        if (tid == 0) s_any = (bl != 0ull);
    }
    __syncthreads();
    if (!s_any) return;

    f32x4 acc;
    int s, p;
    tile32x32(Hnhi, Hnlo, row0, WHLThi, WHLTlo, col0, lds, acc, s, p);
    const int lane = tid & 63;
    __syncthreads();
    f32x4* red = (f32x4*)lds;                       // 3 x 4 x 64 x 16B = 12 KB
    if (p > 0) red[(p - 1) * 256 + s * 64 + lane] = acc;
    __syncthreads();
    float (*st1)[2] = (float(*)[2])(lds + 12288);
    float (*st2)[2] = (float(*)[2])(lds + 12544);
    if (p == 0) {
#pragma unroll
        for (int q = 0; q < 3; ++q) {
            f32x4 o = red[q * 256 + s * 64 + lane];
            acc += o;
        }
        const int frow = s >> 1, fcol = s & 1;
        const int gc = col0 + fcol * 16 + (lane & 15);
        const int gr0 = row0 + frow * 16 + ((lane >> 4) << 2);
        const bool okc = gc < LD;
        const float blv = okc ? BL[gc] : 0.f;
        float m1a[4], m2a[4];
#pragma unroll
        for (int r = 0; r < 4; ++r) {
            const float v = acc[r] + blv;
            if (okc) logits[(size_t)(gr0 + r) * LD + gc] = v;
            m1a[r] = okc ? v : -3.4e38f;
            m2a[r] = -3.4e38f;
        }
#pragma unroll
        for (int off = 1; off < 16; off <<= 1) {
#pragma unroll
            for (int r = 0; r < 4; ++r) {
                float o1 = __shfl_xor(m1a[r], off);
                float o2 = __shfl_xor(m2a[r], off);
                if (o1 > m1a[r]) { m2a[r] = fmaxf(m1a[r], o2); m1a[r] = o1; }
                else m2a[r] = fmaxf(m2a[r], o1);
            }
        }
        if ((lane & 15) == 0) {
            const int rl0 = frow * 16 + ((lane >> 4) << 2);
#pragma unroll
            for (int r = 0; r < 4; ++r) {
                st1[rl0 + r][fcol] = m1a[r];
                st2[rl0 + r][fcol] = m2a[r];
            }
        }
    }
    __syncthreads();
    if (tid < 32) {
        float M1 = st1[tid][0], M2 = st2[tid][0];
        {
            float o1 = st1[tid][1], o2 = st2[tid][1];
            if (o1 > M1) { M2 = fmaxf(M1, o2); M1 = o1; }
            else M2 = fmaxf(M2, o1);
        }
        m1p[(size_t)(row0 + tid) * 32 + (bid & 31)] = M1;
        m2p[(size_t)(row0 + tid) * 32 + (bid & 31)] = M2;
    }
}

// rows never finalized-certified take the last-step logits
__global__ __launch_bounds__(1024) void k_tail(
    const float* __restrict__ logits, const int* __restrict__ active,
    float* __restrict__ out)
{
    const int row0 = blockIdx.x * 64;
    for (int rl = 0; rl < 64; ++rl) {
        const int r = row0 + rl;
        if (active[r] && active[BN + r]) {
            const float* lr = logits + (size_t)r * LD;
            float* orow = out + (size_t)r * LD;
            for (int jj = threadIdx.x; jj < LD; jj += 1024) orow[jj] = lr[jj];
        }
    }
}

// ---------------------------------------------------------------------------
extern "C" void kernel_launch(void* const* d_in, const int* in_sizes, int n_in,
                              void* d_out, int out_size, void* d_ws, size_t ws_size,
                              hipStream_t stream)
{
    const float* x   = (const float*)d_in[0];
    const float* RIH = (const float*)d_in[1];
    const float* RH  = (const float*)d_in[2];
    const float* RHL = (const float*)d_in[3];
    const float* BH  = (const float*)d_in[4];
    const float* BL  = (const float*)d_in[5];
    const float* MIH = (const float*)d_in[6];
    const float* MH  = (const float*)d_in[7];
    const float* MHL = (const float*)d_in[8];
    float* out = (float*)d_out;
    char* w = (char*)d_ws;

    unsigned short* WHThi = (unsigned short*)(w);                 //  8 MB
    unsigned short* WHTlo = (unsigned short*)(w + 8388608);       //  8 MB
    unsigned short* WXhi  = (unsigned short*)(w + 16777216);      //  4 MB (W_IH^T then W_HL^T)
    unsigned short* WXlo  = (unsigned short*)(w + 20971520);      //  4 MB
    float* drive  = (float*)(w + 25165824);                       //  4 MB
    unsigned short* HAhi = (unsigned short*)(w + 29360128);       //  2 MB
    unsigned short* HAlo = (unsigned short*)(w + 31457280);       //  2 MB
    unsigned short* HBhi = (unsigned short*)(w + 33554432);       //  2 MB
    unsigned short* HBlo = (unsigned short*)(w + 35651584);       //  2 MB
    float* logits = (float*)(w + 37748736);                       //  2 MB (ends 39796736)
    float* scal   = (float*)(w + 39796736);                       //  32 B
    int*   active = (int*)(w + 39796800);                         //  2 x 512 x 4
    int*   cnt    = (int*)(w + 39800896);                         //  16 x 4
    float* dhp    = (float*)(w + 39800960);                       //  2 x 512 x 64 x 4 = 256 KB
    float* m1p    = (float*)(w + 40063104);                       //  512 x 32 x 4 = 64 KB
    float* m2p    = (float*)(w + 40128640);                       //  64 KB (ends 40194176)

    k_init<<<4, 256, 0, stream>>>(active, cnt, scal);
    k_colsum_wh<<<256, 256, 0, stream>>>(RH, MH, dhp);            // dhp reused as part_wh
    k_colsum_whl<<<128, 256, 0, stream>>>(RHL, MHL, m1p);         // m1p reused as part_whl
    k_scalars<<<1, 1024, 0, stream>>>(dhp, m1p, scal);
    k_wsplit<<<512, 256, 0, stream>>>(RIH, MIH, WXhi, WXlo, ID, HDm, HDm, scal, -1);
    k_drive_mfma<<<512, 1024, 0, stream>>>(x, WXhi, WXlo, BH, drive);
    k_wsplit<<<1024, 256, 0, stream>>>(RH, MH, WHThi, WHTlo, HDm, HDm, HDm, scal, 2);
    k_wsplit<<<512, 256, 0, stream>>>(RHL, MHL, WXhi, WXlo, HDm, LD, 1024, scal, -1);
    (void)hipMemsetAsync(HAhi, 0, 4194304, stream);   // zeros HAhi + HAlo (contiguous)

    for (int t = 1; t <= TMAXc; ++t) {
        k_p1<<<512, 1024, 0, stream>>>(WHThi, WHTlo, drive, HAhi, HAlo, HBhi, HBlo,
                                       logits, out, active, cnt, scal, dhp, m1p, m2p, t);
        k_p2<<<512, 1024, 0, stream>>>(WXhi, WXlo, BL, HAhi, HAlo, HBhi, HBlo,
                                       logits, active, cnt, m1p, m2p, t);
    }
    k_tail<<<8, 1024, 0, stream>>>(logits, active, out);
}